// Round 1
// baseline (2667.166 us; speedup 1.0000x reference)
//
#include <hip/hip_runtime.h>
#include <hip/hip_bf16.h>
#include <math.h>

#define BATCH 8
#define SEQ 1024
#define D_MODEL 512
#define D_INNER 1024
#define D_STATE 16
#define DT_RANK 32
#define NROWS (BATCH * SEQ)   // 8192

__device__ __forceinline__ float sigmoidf_(float x) { return 1.f / (1.f + __expf(-x)); }

// Generic NT GEMM: C[m,n] = sum_k A[m,k]*B[n,k]
// 128x64 tile, 256 threads, 8x4 microtile, K-tile 16.
// epi: 0 = none, 1 = softplus(acc + bias[n])
// revA: read A rows time-reversed (row = b*1024 + (1023-t))
// revC: write C rows time-reversed; accumC: C += instead of C =
__global__ __launch_bounds__(256) void gemm_nt(
    const float* __restrict__ A, int lda,
    const float* __restrict__ B, int ldb,
    float* __restrict__ C, int ldc,
    int M, int N, int K,
    const float* __restrict__ bias,
    int epi, int revA, int revC, int accumC)
{
  __shared__ float As[16][132];  // 128 + 4 pad (row 528B, 16B aligned)
  __shared__ float Bs[16][68];   // 64 + 4 pad
  const int tid = threadIdx.x;
  const int bm = blockIdx.y << 7;
  const int bn = blockIdx.x << 6;
  const int tm = (tid >> 4) << 3;  // 0..120
  const int tn = (tid & 15) << 2;  // 0..60
  float acc[8][4] = {{0.f}};

  for (int k0 = 0; k0 < K; k0 += 16) {
#pragma unroll
    for (int i = 0; i < 8; ++i) {       // A tile: 128x16 = 2048 elems
      int e = (i << 8) + tid;
      int kk = e & 15, mm = e >> 4;
      int gm = bm + mm;
      int arow = revA ? ((gm & ~1023) + (1023 - (gm & 1023))) : gm;
      As[kk][mm] = A[(long)arow * lda + (k0 + kk)];
    }
#pragma unroll
    for (int i = 0; i < 4; ++i) {       // B tile: 64x16 = 1024 elems
      int e = (i << 8) + tid;
      int kk = e & 15, mm = e >> 4;
      Bs[kk][mm] = B[(long)(bn + mm) * ldb + (k0 + kk)];
    }
    __syncthreads();
#pragma unroll
    for (int kk = 0; kk < 16; ++kk) {
      float a[8], b[4];
#pragma unroll
      for (int i = 0; i < 8; ++i) a[i] = As[kk][tm + i];
#pragma unroll
      for (int j = 0; j < 4; ++j) b[j] = Bs[kk][tn + j];
#pragma unroll
      for (int i = 0; i < 8; ++i)
#pragma unroll
        for (int j = 0; j < 4; ++j)
          acc[i][j] = fmaf(a[i], b[j], acc[i][j]);
    }
    __syncthreads();
  }

#pragma unroll
  for (int i = 0; i < 8; ++i) {
    int m = bm + tm + i;
    int crow = revC ? ((m & ~1023) + (1023 - (m & 1023))) : m;
#pragma unroll
    for (int j = 0; j < 4; ++j) {
      int n = bn + tn + j;
      float v = acc[i][j];
      if (epi == 1) {
        v += bias[n];
        v = (v > 20.f) ? v : log1pf(__expf(v));
      }
      float* p = C + (long)crow * ldc + n;
      if (accumC) *p += v; else *p = v;
    }
  }
}

// Causal depthwise conv1d (kernel 4) + bias + silu.
// uz: [8192, 2048] (u in cols 0..1023), out uc: [8192, 1024]
__global__ __launch_bounds__(256) void conv_silu(
    const float* __restrict__ uz,
    const float* __restrict__ cw,   // [1024,4]
    const float* __restrict__ cb,   // [1024]
    float* __restrict__ uc)
{
  int idx = blockIdx.x * 256 + threadIdx.x;
  if (idx >= NROWS * D_INNER) return;
  int d = idx & (D_INNER - 1);
  int r = idx >> 10;          // b*SEQ + t
  int t = r & (SEQ - 1);
  const float4 w = *(const float4*)(cw + d * 4);
  const float* p = uz + (long)r * (2 * D_INNER) + d;
  float acc = fmaf(w.w, p[0], cb[d]);
  if (t >= 1) acc = fmaf(w.z, p[-2048], acc);
  if (t >= 2) acc = fmaf(w.y, p[-4096], acc);
  if (t >= 3) acc = fmaf(w.x, p[-6144], acc);
  uc[idx] = acc * sigmoidf_(acc);
}

// Selective scan: one thread per (b,d), 16 states in registers.
// Writes ydz[r,d] = (y + u*D) * silu(z) in-place over ucv.
__global__ __launch_bounds__(256) void scan_kernel(
    const float* __restrict__ delta,  // [8192,1024]
    const float* __restrict__ ucv,    // [8192,1024] (u after conv+silu)
    const float* __restrict__ dbl,    // [8192,64]  (B at 32..47, C at 48..63)
    const float* __restrict__ A_log,  // [1024,16]
    const float* __restrict__ Dp,     // [1024]
    const float* __restrict__ uz,     // [8192,2048] (z in cols 1024..2047)
    float* __restrict__ ydz)          // [8192,1024] (aliases ucv)
{
  int idx = blockIdx.x * 256 + threadIdx.x;  // 0..8191
  if (idx >= BATCH * D_INNER) return;
  int d = idx & (D_INNER - 1);
  int b = idx >> 10;
  float Ar[D_STATE];
#pragma unroll
  for (int s = 0; s < D_STATE; ++s) Ar[s] = -__expf(A_log[d * D_STATE + s]);
  float h[D_STATE] = {0.f};
  float Dd = Dp[d];
  const long rowbase = (long)b * SEQ;
  for (int t = 0; t < SEQ; ++t) {
    long r = rowbase + t;
    float dt = delta[r * D_INNER + d];
    float u  = ucv[r * D_INNER + d];
    float du = dt * u;
    const float* bc = dbl + r * 64;
    float y = 0.f;
#pragma unroll
    for (int s = 0; s < D_STATE; ++s) {
      h[s] = fmaf(h[s], __expf(dt * Ar[s]), du * bc[32 + s]);
      y = fmaf(h[s], bc[48 + s], y);
    }
    float z = uz[r * (2 * D_INNER) + D_INNER + d];
    float yv = fmaf(u, Dd, y);
    ydz[r * D_INNER + d] = yv * (z * sigmoidf_(z));
  }
}

extern "C" void kernel_launch(void* const* d_in, const int* in_sizes, int n_in,
                              void* d_out, int out_size, void* d_ws, size_t ws_size,
                              hipStream_t stream)
{
  const float* x = (const float*)d_in[0];
  float* out = (float*)d_out;
  char* ws = (char*)d_ws;
  float* uz    = (float*)(ws);                                        // 64 MB
  float* ucv   = (float*)(ws + 67108864);                             // 32 MB
  float* dbl   = (float*)(ws + 67108864 + 33554432);                  // 2 MB
  float* delta = (float*)(ws + 67108864 + 33554432 + 2097152);        // 32 MB

  dim3 blk(256);
  for (int dir = 0; dir < 2; ++dir) {
    const float* in_w  = (const float*)d_in[1 + dir * 9];
    const float* cw    = (const float*)d_in[2 + dir * 9];
    const float* cb    = (const float*)d_in[3 + dir * 9];
    const float* xp_w  = (const float*)d_in[4 + dir * 9];
    const float* dt_w  = (const float*)d_in[5 + dir * 9];
    const float* dt_b  = (const float*)d_in[6 + dir * 9];
    const float* A_log = (const float*)d_in[7 + dir * 9];
    const float* Dp    = (const float*)d_in[8 + dir * 9];
    const float* out_w = (const float*)d_in[9 + dir * 9];

    // 1) in_proj: uz = xrev @ in_w.T   [8192,2048]
    gemm_nt<<<dim3(2048 / 64, NROWS / 128), blk, 0, stream>>>(
        x, D_MODEL, in_w, D_MODEL, uz, 2 * D_INNER,
        NROWS, 2 * D_INNER, D_MODEL, nullptr, 0, dir, 0, 0);
    // 2) conv + silu -> ucv
    conv_silu<<<dim3(NROWS * D_INNER / 256), blk, 0, stream>>>(uz, cw, cb, ucv);
    // 3) x_proj: dbl = ucv @ xp_w.T   [8192,64]
    gemm_nt<<<dim3(64 / 64, NROWS / 128), blk, 0, stream>>>(
        ucv, D_INNER, xp_w, D_INNER, dbl, 64,
        NROWS, 64, D_INNER, nullptr, 0, 0, 0, 0);
    // 4) dt_proj + softplus: delta = softplus(dbl[:, :32] @ dt_w.T + dt_b)
    gemm_nt<<<dim3(D_INNER / 64, NROWS / 128), blk, 0, stream>>>(
        dbl, 64, dt_w, DT_RANK, delta, D_INNER,
        NROWS, D_INNER, DT_RANK, dt_b, 1, 0, 0, 0);
    // 5) selective scan (writes ydz in-place over ucv)
    scan_kernel<<<dim3((BATCH * D_INNER) / 256), blk, 0, stream>>>(
        delta, ucv, dbl, A_log, Dp, uz, ucv);
    // 6) out_proj: out (+)= ydz @ out_w.T  [8192,512], bwd reversed+accumulated
    gemm_nt<<<dim3(D_MODEL / 64, NROWS / 128), blk, 0, stream>>>(
        ucv, D_INNER, out_w, D_INNER, out, D_MODEL,
        NROWS, D_MODEL, D_INNER, nullptr, 0, 0, dir, dir);
  }
}

// Round 2
// 1194.640 us; speedup vs baseline: 2.2326x; 2.2326x over previous
//
#include <hip/hip_runtime.h>
#include <hip/hip_bf16.h>
#include <math.h>

#define BATCH 8
#define SEQ 1024
#define D_MODEL 512
#define D_INNER 1024
#define D_STATE 16
#define DT_RANK 32
#define NROWS (BATCH * SEQ)   // 8192
#define CH 32                 // chunks per sequence
#define CL 32                 // chunk length (CH*CL == SEQ)

__device__ __forceinline__ float sigmoidf_(float x) { return 1.f / (1.f + __expf(-x)); }

// Generic NT GEMM: C[m,n] = sum_k A[m,k]*B[n,k]
// 128x64 tile, 256 threads, 8x4 microtile, K-tile 16.
__global__ __launch_bounds__(256) void gemm_nt(
    const float* __restrict__ A, int lda,
    const float* __restrict__ B, int ldb,
    float* __restrict__ C, int ldc,
    int M, int N, int K,
    const float* __restrict__ bias,
    int epi, int revA, int revC, int accumC)
{
  __shared__ float As[16][132];
  __shared__ float Bs[16][68];
  const int tid = threadIdx.x;
  const int bm = blockIdx.y << 7;
  const int bn = blockIdx.x << 6;
  const int tm = (tid >> 4) << 3;
  const int tn = (tid & 15) << 2;
  float acc[8][4] = {{0.f}};

  for (int k0 = 0; k0 < K; k0 += 16) {
#pragma unroll
    for (int i = 0; i < 8; ++i) {
      int e = (i << 8) + tid;
      int kk = e & 15, mm = e >> 4;
      int gm = bm + mm;
      int arow = revA ? ((gm & ~1023) + (1023 - (gm & 1023))) : gm;
      As[kk][mm] = A[(long)arow * lda + (k0 + kk)];
    }
#pragma unroll
    for (int i = 0; i < 4; ++i) {
      int e = (i << 8) + tid;
      int kk = e & 15, mm = e >> 4;
      Bs[kk][mm] = B[(long)(bn + mm) * ldb + (k0 + kk)];
    }
    __syncthreads();
#pragma unroll
    for (int kk = 0; kk < 16; ++kk) {
      float a[8], b[4];
#pragma unroll
      for (int i = 0; i < 8; ++i) a[i] = As[kk][tm + i];
#pragma unroll
      for (int j = 0; j < 4; ++j) b[j] = Bs[kk][tn + j];
#pragma unroll
      for (int i = 0; i < 8; ++i)
#pragma unroll
        for (int j = 0; j < 4; ++j)
          acc[i][j] = fmaf(a[i], b[j], acc[i][j]);
    }
    __syncthreads();
  }

#pragma unroll
  for (int i = 0; i < 8; ++i) {
    int m = bm + tm + i;
    int crow = revC ? ((m & ~1023) + (1023 - (m & 1023))) : m;
#pragma unroll
    for (int j = 0; j < 4; ++j) {
      int n = bn + tn + j;
      float v = acc[i][j];
      if (epi == 1) {
        v += bias[n];
        v = (v > 20.f) ? v : log1pf(__expf(v));
      }
      float* p = C + (long)crow * ldc + n;
      if (accumC) *p += v; else *p = v;
    }
  }
}

// Causal depthwise conv1d (kernel 4) + bias + silu.
__global__ __launch_bounds__(256) void conv_silu(
    const float* __restrict__ uz,
    const float* __restrict__ cw,
    const float* __restrict__ cb,
    float* __restrict__ uc)
{
  int idx = blockIdx.x * 256 + threadIdx.x;
  if (idx >= NROWS * D_INNER) return;
  int d = idx & (D_INNER - 1);
  int r = idx >> 10;
  int t = r & (SEQ - 1);
  const float4 w = *(const float4*)(cw + d * 4);
  const float* p = uz + (long)r * (2 * D_INNER) + d;
  float acc = fmaf(w.w, p[0], cb[d]);
  if (t >= 1) acc = fmaf(w.z, p[-2048], acc);
  if (t >= 2) acc = fmaf(w.y, p[-4096], acc);
  if (t >= 3) acc = fmaf(w.x, p[-6144], acc);
  uc[idx] = acc * sigmoidf_(acc);
}

// Pass A: chunk-local scan from h=0. Thread per (b, chunk, d).
// Stores end state hend[b][c][s][d] and dtsum[b][c][d].
__global__ __launch_bounds__(256) void scan_partA(
    const float* __restrict__ delta,  // [8192,2048] stride 2048 (in uz u-half)
    const float* __restrict__ ucv,    // [8192,1024]
    const float* __restrict__ dbl,    // [8192,64]
    const float* __restrict__ A_log,  // [1024,16]
    float* __restrict__ hend,         // [8][CH][16][1024]
    float* __restrict__ dtsum_buf)    // [8][CH][1024]
{
  int idx = blockIdx.x * 256 + threadIdx.x;      // 0 .. 8*CH*1024-1
  int d = idx & 1023;
  int c = (idx >> 10) & (CH - 1);
  int b = idx >> 15;
  float Ar[D_STATE];
#pragma unroll
  for (int s = 0; s < D_STATE; ++s) Ar[s] = -__expf(A_log[d * D_STATE + s]);
  float h[D_STATE] = {0.f};
  float dtsum = 0.f;
  const long r0 = (long)b * SEQ + c * CL;
  for (int t = 0; t < CL; ++t) {
    long r = r0 + t;
    float dt = delta[r * 2048 + d];
    float u  = ucv[r * 1024 + d];
    float du = dt * u;
    const float* bc = dbl + r * 64;
    dtsum += dt;
#pragma unroll
    for (int s = 0; s < D_STATE; ++s)
      h[s] = fmaf(h[s], __expf(dt * Ar[s]), du * bc[32 + s]);
  }
  long base = ((long)(b * CH + c) * D_STATE) * 1024 + d;
#pragma unroll
  for (int s = 0; s < D_STATE; ++s) hend[base + s * 1024] = h[s];
  dtsum_buf[(long)(b * CH + c) * 1024 + d] = dtsum;
}

// Pass B: sequential combine over chunks. Thread per (b,d,s).
// Rewrites hend in place with chunk INITIAL states.
__global__ __launch_bounds__(256) void scan_partB(
    float* __restrict__ hend,         // [8][CH][16][1024] in: local end, out: init
    const float* __restrict__ dtsum_buf,
    const float* __restrict__ A_log)
{
  int idx = blockIdx.x * 256 + threadIdx.x;      // 0 .. 8*16*1024-1
  int d = idx & 1023;
  int s = (idx >> 10) & 15;
  int b = idx >> 14;
  float Ars = -__expf(A_log[d * D_STATE + s]);
  float H = 0.f;
  for (int c = 0; c < CH; ++c) {
    long off = ((long)(b * CH + c) * D_STATE + s) * 1024 + d;
    float he = hend[off];
    float P = __expf(Ars * dtsum_buf[(long)(b * CH + c) * 1024 + d]);
    hend[off] = H;                   // chunk c initial state
    H = fmaf(P, H, he);              // running true end state
  }
}

// Pass C: re-scan each chunk from true initial state; fused y*silu(z) output.
__global__ __launch_bounds__(256) void scan_partC(
    const float* __restrict__ delta,  // stride 2048
    const float* __restrict__ ucv,
    const float* __restrict__ dbl,
    const float* __restrict__ A_log,
    const float* __restrict__ Dp,
    const float* __restrict__ uz,     // z at col 1024+d, stride 2048
    const float* __restrict__ hinit,  // [8][CH][16][1024]
    float* __restrict__ ydz)          // [8192,1024] (aliases ucv)
{
  int idx = blockIdx.x * 256 + threadIdx.x;
  int d = idx & 1023;
  int c = (idx >> 10) & (CH - 1);
  int b = idx >> 15;
  float Ar[D_STATE];
#pragma unroll
  for (int s = 0; s < D_STATE; ++s) Ar[s] = -__expf(A_log[d * D_STATE + s]);
  float h[D_STATE];
  long base = ((long)(b * CH + c) * D_STATE) * 1024 + d;
#pragma unroll
  for (int s = 0; s < D_STATE; ++s) h[s] = hinit[base + s * 1024];
  float Dd = Dp[d];
  const long r0 = (long)b * SEQ + c * CL;
  for (int t = 0; t < CL; ++t) {
    long r = r0 + t;
    float dt = delta[r * 2048 + d];
    float u  = ucv[r * 1024 + d];
    float du = dt * u;
    const float* bc = dbl + r * 64;
    float y = 0.f;
#pragma unroll
    for (int s = 0; s < D_STATE; ++s) {
      h[s] = fmaf(h[s], __expf(dt * Ar[s]), du * bc[32 + s]);
      y = fmaf(h[s], bc[48 + s], y);
    }
    float z = uz[r * 2048 + 1024 + d];
    float yv = fmaf(u, Dd, y);
    ydz[r * 1024 + d] = yv * (z * sigmoidf_(z));
  }
}

extern "C" void kernel_launch(void* const* d_in, const int* in_sizes, int n_in,
                              void* d_out, int out_size, void* d_ws, size_t ws_size,
                              hipStream_t stream)
{
  const float* x = (const float*)d_in[0];
  float* out = (float*)d_out;
  char* ws = (char*)d_ws;
  float* uz    = (float*)(ws);                       // 64 MB [8192,2048]
  float* ucv   = (float*)(ws + (64u << 20));         // 32 MB [8192,1024]
  float* dbl   = (float*)(ws + (96u << 20));         //  2 MB [8192,64]
  float* hend  = (float*)(ws + (98u << 20));         // 16 MB [8][CH][16][1024]
  float* dtsum = (float*)(ws + (114u << 20));        //  1 MB [8][CH][1024]
  float* delta = uz;                                 // u-half of uz, stride 2048

  dim3 blk(256);
  const int scanAC_blocks = BATCH * CH * 1024 / 256;   // 1024
  const int scanB_blocks  = BATCH * 16 * 1024 / 256;   // 512

  for (int dir = 0; dir < 2; ++dir) {
    const float* in_w  = (const float*)d_in[1 + dir * 9];
    const float* cw    = (const float*)d_in[2 + dir * 9];
    const float* cb    = (const float*)d_in[3 + dir * 9];
    const float* xp_w  = (const float*)d_in[4 + dir * 9];
    const float* dt_w  = (const float*)d_in[5 + dir * 9];
    const float* dt_b  = (const float*)d_in[6 + dir * 9];
    const float* A_log = (const float*)d_in[7 + dir * 9];
    const float* Dp    = (const float*)d_in[8 + dir * 9];
    const float* out_w = (const float*)d_in[9 + dir * 9];

    // 1) in_proj: uz = x(rev) @ in_w.T   [8192,2048]
    gemm_nt<<<dim3(2048 / 64, NROWS / 128), blk, 0, stream>>>(
        x, D_MODEL, in_w, D_MODEL, uz, 2 * D_INNER,
        NROWS, 2 * D_INNER, D_MODEL, nullptr, 0, dir, 0, 0);
    // 2) conv + silu -> ucv
    conv_silu<<<dim3(NROWS * D_INNER / 256), blk, 0, stream>>>(uz, cw, cb, ucv);
    // 3) x_proj: dbl = ucv @ xp_w.T   [8192,64]
    gemm_nt<<<dim3(1, NROWS / 128), blk, 0, stream>>>(
        ucv, D_INNER, xp_w, D_INNER, dbl, 64,
        NROWS, 64, D_INNER, nullptr, 0, 0, 0, 0);
    // 4) dt_proj + softplus -> delta (u-half of uz, ldc=2048)
    gemm_nt<<<dim3(D_INNER / 64, NROWS / 128), blk, 0, stream>>>(
        dbl, 64, dt_w, DT_RANK, delta, 2048,
        NROWS, D_INNER, DT_RANK, dt_b, 1, 0, 0, 0);
    // 5) chunked scan
    scan_partA<<<dim3(scanAC_blocks), blk, 0, stream>>>(
        delta, ucv, dbl, A_log, hend, dtsum);
    scan_partB<<<dim3(scanB_blocks), blk, 0, stream>>>(hend, dtsum, A_log);
    scan_partC<<<dim3(scanAC_blocks), blk, 0, stream>>>(
        delta, ucv, dbl, A_log, Dp, uz, hend, ucv);
    // 6) out_proj: out (+)= ydz @ out_w.T  [8192,512]
    gemm_nt<<<dim3(D_MODEL / 64, NROWS / 128), blk, 0, stream>>>(
        ucv, D_INNER, out_w, D_INNER, out, D_MODEL,
        NROWS, D_MODEL, D_INNER, nullptr, 0, 0, dir, dir);
  }
}

// Round 3
// 499.094 us; speedup vs baseline: 5.3440x; 2.3936x over previous
//
#include <hip/hip_runtime.h>
#include <hip/hip_bf16.h>
#include <math.h>

#define BATCH 8
#define SEQ 1024
#define D_MODEL 512
#define D_INNER 1024
#define D_STATE 16
#define DT_RANK 32
#define NROWS (BATCH * SEQ)   // 8192
#define CH 32
#define CL 32

typedef short short8 __attribute__((ext_vector_type(8)));
typedef float f32x4 __attribute__((ext_vector_type(4)));

__device__ __forceinline__ float sigmoidf_(float x) { return 1.f / (1.f + __expf(-x)); }

// fp32 -> bf16 RNE
__device__ __forceinline__ ushort f2b(float f) {
  uint u = __float_as_uint(f);
  return (ushort)((u + 0x7FFFu + ((u >> 16) & 1u)) >> 16);
}

__device__ __forceinline__ void gload16(const ushort* g, const ushort* l) {
  __builtin_amdgcn_global_load_lds(
      (const __attribute__((address_space(1))) void*)g,
      (__attribute__((address_space(3))) void*)l, 16, 0, 0);
}

// ---------------- bf16 MFMA GEMM (m97 structure) ----------------
// C[m,n] = sum_k A[m,k]*B[n,k]; A:[M,lda] bf16, B:[N,ldb] bf16, C fp32.
// 128xBN tile, 256 threads (4 waves), wave grid RW x CW, BK=32.
template<int BN, int RW, int CW>
__global__ __launch_bounds__(256) void gemm_bf16(
    const ushort* __restrict__ A, int lda,
    const ushort* __restrict__ B, int ldb,
    float* __restrict__ C, int ldc,
    int K, int revA, int revC, int accumC)
{
  constexpr int MI = 128 / RW / 16;   // frag rows per wave
  constexpr int NJ = BN / CW / 16;    // frag cols per wave
  __shared__ ushort As[128 * 32];
  __shared__ ushort Bs[BN * 32];
  const int tid = threadIdx.x;
  const int w = tid >> 6, lane = tid & 63;
  const int bm = blockIdx.y * 128;
  const int bn = blockIdx.x * BN;
  const int rw0 = (w / CW) * (MI * 16);
  const int cw0 = (w % CW) * (NJ * 16);
  const int srow = w * 16 + (lane >> 2);   // staging row within 64-row group
  const int scol = (lane & 3) * 8;         // staging k-offset (elems)

  f32x4 acc[MI][NJ] = {};

  for (int k0 = 0; k0 < K; k0 += 32) {
#pragma unroll
    for (int it = 0; it < 2; ++it) {       // A tile: 128 rows
      int gm = bm + it * 64 + srow;
      int arow = revA ? ((gm & ~1023) | (1023 - (gm & 1023))) : gm;
      gload16(A + (long)arow * lda + k0 + scol, &As[(it * 64 + w * 16) * 32]);
    }
#pragma unroll
    for (int it = 0; it < BN / 64; ++it) { // B tile: BN rows
      int gn = bn + it * 64 + srow;
      gload16(B + (long)gn * ldb + k0 + scol, &Bs[(it * 64 + w * 16) * 32]);
    }
    __syncthreads();
    short8 a[MI], b[NJ];
#pragma unroll
    for (int i = 0; i < MI; ++i)
      a[i] = *(const short8*)&As[(rw0 + i * 16 + (lane & 15)) * 32 + (lane >> 4) * 8];
#pragma unroll
    for (int j = 0; j < NJ; ++j)
      b[j] = *(const short8*)&Bs[(cw0 + j * 16 + (lane & 15)) * 32 + (lane >> 4) * 8];
#pragma unroll
    for (int i = 0; i < MI; ++i)
#pragma unroll
      for (int j = 0; j < NJ; ++j)
        acc[i][j] = __builtin_amdgcn_mfma_f32_16x16x32_bf16(a[i], b[j], acc[i][j], 0, 0, 0);
    __syncthreads();
  }

#pragma unroll
  for (int i = 0; i < MI; ++i)
#pragma unroll
    for (int r = 0; r < 4; ++r) {
      int m = bm + rw0 + i * 16 + (lane >> 4) * 4 + r;
      int crow = revC ? ((m & ~1023) | (1023 - (m & 1023))) : m;
#pragma unroll
      for (int j = 0; j < NJ; ++j) {
        int n = bn + cw0 + j * 16 + (lane & 15);
        float* p = C + (long)crow * ldc + n;
        float v = acc[i][j][r];
        if (accumC) *p += v; else *p = v;
      }
    }
}

// ---------------- fp32 vector GEMM (dt_proj only, K=32) ----------------
__global__ __launch_bounds__(256) void gemm_nt(
    const float* __restrict__ A, int lda,
    const float* __restrict__ B, int ldb,
    float* __restrict__ C, int ldc,
    int M, int N, int K,
    const float* __restrict__ bias, int epi)
{
  __shared__ float As[16][132];
  __shared__ float Bs[16][68];
  const int tid = threadIdx.x;
  const int bm = blockIdx.y << 7;
  const int bn = blockIdx.x << 6;
  const int tm = (tid >> 4) << 3;
  const int tn = (tid & 15) << 2;
  float acc[8][4] = {{0.f}};

  for (int k0 = 0; k0 < K; k0 += 16) {
#pragma unroll
    for (int i = 0; i < 8; ++i) {
      int e = (i << 8) + tid;
      int kk = e & 15, mm = e >> 4;
      As[kk][mm] = A[(long)(bm + mm) * lda + (k0 + kk)];
    }
#pragma unroll
    for (int i = 0; i < 4; ++i) {
      int e = (i << 8) + tid;
      int kk = e & 15, mm = e >> 4;
      Bs[kk][mm] = B[(long)(bn + mm) * ldb + (k0 + kk)];
    }
    __syncthreads();
#pragma unroll
    for (int kk = 0; kk < 16; ++kk) {
      float a[8], b[4];
#pragma unroll
      for (int i = 0; i < 8; ++i) a[i] = As[kk][tm + i];
#pragma unroll
      for (int j = 0; j < 4; ++j) b[j] = Bs[kk][tn + j];
#pragma unroll
      for (int i = 0; i < 8; ++i)
#pragma unroll
        for (int j = 0; j < 4; ++j)
          acc[i][j] = fmaf(a[i], b[j], acc[i][j]);
    }
    __syncthreads();
  }
#pragma unroll
  for (int i = 0; i < 8; ++i)
#pragma unroll
    for (int j = 0; j < 4; ++j) {
      int n = bn + tn + j;
      float v = acc[i][j];
      if (epi == 1) {
        v += bias[n];
        v = (v > 20.f) ? v : log1pf(__expf(v));
      }
      C[(long)(bm + tm + i) * ldc + n] = v;
    }
}

// fp32 -> bf16 conversion, 4 elems/thread
__global__ __launch_bounds__(256) void f2bf4(const float4* __restrict__ in,
                                             ushort4* __restrict__ out, int n4)
{
  int i = blockIdx.x * 256 + threadIdx.x;
  if (i >= n4) return;
  float4 v = in[i];
  ushort4 o;
  o.x = f2b(v.x); o.y = f2b(v.y); o.z = f2b(v.z); o.w = f2b(v.w);
  out[i] = o;
}

// conv1d(k=4) + bias + silu -> ucv (fp32) + ucv_bf (bf16)
__global__ __launch_bounds__(256) void conv_silu(
    const float* __restrict__ uz,
    const float* __restrict__ cw,
    const float* __restrict__ cb,
    float* __restrict__ uc,
    ushort* __restrict__ uc_bf)
{
  int idx = blockIdx.x * 256 + threadIdx.x;
  if (idx >= NROWS * D_INNER) return;
  int d = idx & (D_INNER - 1);
  int r = idx >> 10;
  int t = r & (SEQ - 1);
  const float4 w = *(const float4*)(cw + d * 4);
  const float* p = uz + (long)r * 2048 + d;
  float acc = fmaf(w.w, p[0], cb[d]);
  if (t >= 1) acc = fmaf(w.z, p[-2048], acc);
  if (t >= 2) acc = fmaf(w.y, p[-4096], acc);
  if (t >= 3) acc = fmaf(w.x, p[-6144], acc);
  float v = acc * sigmoidf_(acc);
  uc[idx] = v;
  uc_bf[idx] = f2b(v);
}

// Pass A: chunk-local scan from h=0
__global__ __launch_bounds__(256) void scan_partA(
    const float* __restrict__ delta,  // stride 2048
    const float* __restrict__ ucv,
    const float* __restrict__ dbl,
    const float* __restrict__ A_log,
    float* __restrict__ hend,
    float* __restrict__ dtsum_buf)
{
  int idx = blockIdx.x * 256 + threadIdx.x;
  int d = idx & 1023;
  int c = (idx >> 10) & (CH - 1);
  int b = idx >> 15;
  float Ar[D_STATE];
#pragma unroll
  for (int s = 0; s < D_STATE; ++s) Ar[s] = -__expf(A_log[d * D_STATE + s]);
  float h[D_STATE] = {0.f};
  float dtsum = 0.f;
  const long r0 = (long)b * SEQ + c * CL;
  for (int t = 0; t < CL; ++t) {
    long r = r0 + t;
    float dt = delta[r * 2048 + d];
    float u  = ucv[r * 1024 + d];
    float du = dt * u;
    const float* bc = dbl + r * 64;
    dtsum += dt;
#pragma unroll
    for (int s = 0; s < D_STATE; ++s)
      h[s] = fmaf(h[s], __expf(dt * Ar[s]), du * bc[32 + s]);
  }
  long base = ((long)(b * CH + c) * D_STATE) * 1024 + d;
#pragma unroll
  for (int s = 0; s < D_STATE; ++s) hend[base + s * 1024] = h[s];
  dtsum_buf[(long)(b * CH + c) * 1024 + d] = dtsum;
}

// Pass B: sequential chunk combine; hend -> chunk initial states
__global__ __launch_bounds__(256) void scan_partB(
    float* __restrict__ hend,
    const float* __restrict__ dtsum_buf,
    const float* __restrict__ A_log)
{
  int idx = blockIdx.x * 256 + threadIdx.x;
  int d = idx & 1023;
  int s = (idx >> 10) & 15;
  int b = idx >> 14;
  float Ars = -__expf(A_log[d * D_STATE + s]);
  float H = 0.f;
  for (int c = 0; c < CH; ++c) {
    long off = ((long)(b * CH + c) * D_STATE + s) * 1024 + d;
    float he = hend[off];
    float P = __expf(Ars * dtsum_buf[(long)(b * CH + c) * 1024 + d]);
    hend[off] = H;
    H = fmaf(P, H, he);
  }
}

// Pass C: re-scan from true initial state; fused (y+uD)*silu(z) -> bf16
__global__ __launch_bounds__(256) void scan_partC(
    const float* __restrict__ delta,
    const float* __restrict__ ucv,
    const float* __restrict__ dbl,
    const float* __restrict__ A_log,
    const float* __restrict__ Dp,
    const float* __restrict__ uz,     // z at col 1024+d
    const float* __restrict__ hinit,
    ushort* __restrict__ ydz_bf)
{
  int idx = blockIdx.x * 256 + threadIdx.x;
  int d = idx & 1023;
  int c = (idx >> 10) & (CH - 1);
  int b = idx >> 15;
  float Ar[D_STATE];
#pragma unroll
  for (int s = 0; s < D_STATE; ++s) Ar[s] = -__expf(A_log[d * D_STATE + s]);
  float h[D_STATE];
  long base = ((long)(b * CH + c) * D_STATE) * 1024 + d;
#pragma unroll
  for (int s = 0; s < D_STATE; ++s) h[s] = hinit[base + s * 1024];
  float Dd = Dp[d];
  const long r0 = (long)b * SEQ + c * CL;
  for (int t = 0; t < CL; ++t) {
    long r = r0 + t;
    float dt = delta[r * 2048 + d];
    float u  = ucv[r * 1024 + d];
    float du = dt * u;
    const float* bc = dbl + r * 64;
    float y = 0.f;
#pragma unroll
    for (int s = 0; s < D_STATE; ++s) {
      h[s] = fmaf(h[s], __expf(dt * Ar[s]), du * bc[32 + s]);
      y = fmaf(h[s], bc[48 + s], y);
    }
    float z = uz[r * 2048 + 1024 + d];
    float yv = fmaf(u, Dd, y);
    ydz_bf[r * 1024 + d] = f2b(yv * (z * sigmoidf_(z)));
  }
}

extern "C" void kernel_launch(void* const* d_in, const int* in_sizes, int n_in,
                              void* d_out, int out_size, void* d_ws, size_t ws_size,
                              hipStream_t stream)
{
  const float* x = (const float*)d_in[0];
  float* out = (float*)d_out;
  char* ws = (char*)d_ws;
  float*  uz     = (float*)(ws);                         // 64 MB [8192,2048]
  float*  ucv    = (float*)(ws + (64u  << 20));          // 32 MB
  float*  dbl    = (float*)(ws + (96u  << 20));          //  2 MB
  float*  hend   = (float*)(ws + (98u  << 20));          // 16 MB
  float*  dtsum  = (float*)(ws + (114u << 20));          //  1 MB
  ushort* xbf    = (ushort*)(ws + (115u << 20));         //  8 MB [8192,512]
  ushort* ucv_bf = (ushort*)(ws + (123u << 20));         // 16 MB (aliased ydz_bf)
  ushort* in_wb  = (ushort*)(ws + (139u << 20));         //  2 MB
  ushort* xp_wb  = (ushort*)(ws + (141u << 20));         // 128 KB
  ushort* out_wb = (ushort*)(ws + (141u << 20) + (512u << 10)); // 1 MB
  ushort* ydz_bf = ucv_bf;
  float*  delta  = uz;                                   // u-half, stride 2048

  dim3 blk(256);
  const int scanAC_blocks = BATCH * CH * 1024 / 256;
  const int scanB_blocks  = BATCH * 16 * 1024 / 256;

  // x -> bf16 once (reversal handled by revA in in_proj)
  f2bf4<<<dim3(NROWS * D_MODEL / 4 / 256), blk, 0, stream>>>(
      (const float4*)x, (ushort4*)xbf, NROWS * D_MODEL / 4);

  for (int dir = 0; dir < 2; ++dir) {
    const float* in_w  = (const float*)d_in[1 + dir * 9];
    const float* cw    = (const float*)d_in[2 + dir * 9];
    const float* cb    = (const float*)d_in[3 + dir * 9];
    const float* xp_w  = (const float*)d_in[4 + dir * 9];
    const float* dt_w  = (const float*)d_in[5 + dir * 9];
    const float* dt_b  = (const float*)d_in[6 + dir * 9];
    const float* A_log = (const float*)d_in[7 + dir * 9];
    const float* Dp    = (const float*)d_in[8 + dir * 9];
    const float* out_w = (const float*)d_in[9 + dir * 9];

    // weights -> bf16
    f2bf4<<<dim3(2048 * 512 / 4 / 256), blk, 0, stream>>>(
        (const float4*)in_w, (ushort4*)in_wb, 2048 * 512 / 4);
    f2bf4<<<dim3(64 * 1024 / 4 / 256), blk, 0, stream>>>(
        (const float4*)xp_w, (ushort4*)xp_wb, 64 * 1024 / 4);
    f2bf4<<<dim3(512 * 1024 / 4 / 256), blk, 0, stream>>>(
        (const float4*)out_w, (ushort4*)out_wb, 512 * 1024 / 4);

    // 1) in_proj: uz = x(rev) @ in_w.T   [8192,2048] (MFMA bf16)
    gemm_bf16<128, 2, 2><<<dim3(2048 / 128, NROWS / 128), blk, 0, stream>>>(
        xbf, D_MODEL, in_wb, D_MODEL, uz, 2048, D_MODEL, dir, 0, 0);
    // 2) conv + silu
    conv_silu<<<dim3(NROWS * D_INNER / 256), blk, 0, stream>>>(
        uz, cw, cb, ucv, ucv_bf);
    // 3) x_proj: dbl = ucv @ xp_w.T   [8192,64] (MFMA bf16, 128x64 tile)
    gemm_bf16<64, 4, 1><<<dim3(1, NROWS / 128), blk, 0, stream>>>(
        ucv_bf, D_INNER, xp_wb, D_INNER, dbl, 64, D_INNER, 0, 0, 0);
    // 4) dt_proj + softplus -> delta (fp32, K=32)
    gemm_nt<<<dim3(D_INNER / 64, NROWS / 128), blk, 0, stream>>>(
        dbl, 64, dt_w, DT_RANK, delta, 2048,
        NROWS, D_INNER, DT_RANK, dt_b, 1);
    // 5) chunked scan
    scan_partA<<<dim3(scanAC_blocks), blk, 0, stream>>>(
        delta, ucv, dbl, A_log, hend, dtsum);
    scan_partB<<<dim3(scanB_blocks), blk, 0, stream>>>(hend, dtsum, A_log);
    scan_partC<<<dim3(scanAC_blocks), blk, 0, stream>>>(
        delta, ucv, dbl, A_log, Dp, uz, hend, ydz_bf);
    // 6) out_proj: out (+)= ydz @ out_w.T  [8192,512] (MFMA bf16)
    gemm_bf16<128, 2, 2><<<dim3(512 / 128, NROWS / 128), blk, 0, stream>>>(
        ydz_bf, D_INNER, out_wb, D_INNER, out, D_MODEL, D_INNER, 0, dir, dir);
  }
}

// Round 4
// 462.722 us; speedup vs baseline: 5.7641x; 1.0786x over previous
//
#include <hip/hip_runtime.h>
#include <math.h>

#define BATCH 8
#define SEQ 1024
#define D_MODEL 512
#define D_INNER 1024
#define D_STATE 16
#define DT_RANK 32
#define NROWS (BATCH * SEQ)   // 8192
#define CH 32
#define CL 32

typedef short short8 __attribute__((ext_vector_type(8)));
typedef float f32x4 __attribute__((ext_vector_type(4)));

__device__ __forceinline__ float sigmoidf_(float x) { return 1.f / (1.f + __expf(-x)); }

__device__ __forceinline__ ushort f2b(float f) {  // fp32 -> bf16 RNE
  uint u = __float_as_uint(f);
  return (ushort)((u + 0x7FFFu + ((u >> 16) & 1u)) >> 16);
}
__device__ __forceinline__ float b2f(ushort u) {
  return __uint_as_float(((uint)u) << 16);
}

__device__ __forceinline__ void gload16(const ushort* g, const ushort* l) {
  __builtin_amdgcn_global_load_lds(
      (const __attribute__((address_space(1))) void*)g,
      (__attribute__((address_space(3))) void*)l, 16, 0, 0);
}

// ---------------- bf16 MFMA GEMM (m97 structure) ----------------
// C[m,n] = sum_k A[m,k]*B[n,k]; 128xBN tile, 4 waves, BK=32.
// EPI: 0 = fp32 store (revC/accumC), 1 = softplus(v+bias[n]) -> bf16,
//      2 = in_proj split (n<1024 -> u bf16; n>=1024 -> silu -> zsilu bf16),
//      3 = dual store fp32 + bf16
template<int BN, int RW, int CW, int EPI>
__global__ __launch_bounds__(256) void gemm_bf16(
    const ushort* __restrict__ A, int lda,
    const ushort* __restrict__ B, int ldb,
    float* __restrict__ Cf, ushort* __restrict__ Cb, ushort* __restrict__ Cb2,
    int ldc, int K, const float* __restrict__ bias,
    int revA, int revC, int accumC)
{
  constexpr int MI = 128 / RW / 16;
  constexpr int NJ = BN / CW / 16;
  __shared__ ushort As[128 * 32];
  __shared__ ushort Bs[BN * 32];
  const int tid = threadIdx.x;
  const int w = tid >> 6, lane = tid & 63;
  const int bm = blockIdx.y * 128;
  const int bn = blockIdx.x * BN;
  const int rw0 = (w / CW) * (MI * 16);
  const int cw0 = (w % CW) * (NJ * 16);
  const int srow = w * 16 + (lane >> 2);
  const int scol = (lane & 3) * 8;

  f32x4 acc[MI][NJ] = {};

  for (int k0 = 0; k0 < K; k0 += 32) {
#pragma unroll
    for (int it = 0; it < 2; ++it) {
      int gm = bm + it * 64 + srow;
      int arow = revA ? ((gm & ~1023) | (1023 - (gm & 1023))) : gm;
      gload16(A + (long)arow * lda + k0 + scol, &As[(it * 64 + w * 16) * 32]);
    }
#pragma unroll
    for (int it = 0; it < BN / 64; ++it) {
      int gn = bn + it * 64 + srow;
      gload16(B + (long)gn * ldb + k0 + scol, &Bs[(it * 64 + w * 16) * 32]);
    }
    __syncthreads();
    short8 a[MI], b[NJ];
#pragma unroll
    for (int i = 0; i < MI; ++i)
      a[i] = *(const short8*)&As[(rw0 + i * 16 + (lane & 15)) * 32 + (lane >> 4) * 8];
#pragma unroll
    for (int j = 0; j < NJ; ++j)
      b[j] = *(const short8*)&Bs[(cw0 + j * 16 + (lane & 15)) * 32 + (lane >> 4) * 8];
#pragma unroll
    for (int i = 0; i < MI; ++i)
#pragma unroll
      for (int j = 0; j < NJ; ++j)
        acc[i][j] = __builtin_amdgcn_mfma_f32_16x16x32_bf16(a[i], b[j], acc[i][j], 0, 0, 0);
    __syncthreads();
  }

#pragma unroll
  for (int i = 0; i < MI; ++i)
#pragma unroll
    for (int r = 0; r < 4; ++r) {
      int m = bm + rw0 + i * 16 + (lane >> 4) * 4 + r;
      int crow = revC ? ((m & ~1023) | (1023 - (m & 1023))) : m;
#pragma unroll
      for (int j = 0; j < NJ; ++j) {
        int n = bn + cw0 + j * 16 + (lane & 15);
        float v = acc[i][j][r];
        if (EPI == 0) {
          float* p = Cf + (long)crow * ldc + n;
          if (accumC) *p += v; else *p = v;
        } else if (EPI == 1) {
          v += bias[n];
          v = (v > 20.f) ? v : log1pf(__expf(v));
          Cb[(long)crow * ldc + n] = f2b(v);
        } else if (EPI == 2) {
          if (n < D_INNER) Cb[(long)crow * D_INNER + n] = f2b(v);
          else Cb2[(long)crow * D_INNER + (n - D_INNER)] = f2b(v * sigmoidf_(v));
        } else {  // EPI == 3
          Cf[(long)crow * ldc + n] = v;
          Cb[(long)crow * ldc + n] = f2b(v);
        }
      }
    }
}

// ---------------- fused fp32->bf16 converter (x + 8 weight tensors) --------
struct Seg { const float4* s; ushort4* d; int n4; int bstart; };
struct ConvArgs { Seg seg[9]; };

__global__ __launch_bounds__(256) void convert_all(ConvArgs a)
{
  int blk = blockIdx.x;
  int i = 0;
#pragma unroll
  for (int k = 1; k < 9; ++k) if (blk >= a.seg[k].bstart) i = k;
  int idx = (blk - a.seg[i].bstart) * 256 + threadIdx.x;
  if (idx >= a.seg[i].n4) return;
  float4 v = a.seg[i].s[idx];
  ushort4 o;
  o.x = f2b(v.x); o.y = f2b(v.y); o.z = f2b(v.z); o.w = f2b(v.w);
  a.seg[i].d[idx] = o;
}

// ---------------- conv1d(k=4) + bias + silu (bf16 in/out, 4 d/thread) ------
__global__ __launch_bounds__(256) void conv_silu(
    const ushort* __restrict__ u_bf,   // [8192,1024]
    const float* __restrict__ cw,      // [1024,4]
    const float* __restrict__ cb,      // [1024]
    ushort* __restrict__ uc_bf)        // [8192,1024]
{
  int i = blockIdx.x * 256 + threadIdx.x;   // 0 .. 8192*256-1
  int r = i >> 8;
  int d0 = (i & 255) << 2;
  int t = r & (SEQ - 1);
  const ushort* p = u_bf + (long)r * D_INNER + d0;
  ushort4 u0 = *(const ushort4*)p;
  ushort4 u1 = (t >= 1) ? *(const ushort4*)(p - 1024) : ushort4{0, 0, 0, 0};
  ushort4 u2 = (t >= 2) ? *(const ushort4*)(p - 2048) : ushort4{0, 0, 0, 0};
  ushort4 u3 = (t >= 3) ? *(const ushort4*)(p - 3072) : ushort4{0, 0, 0, 0};
  float4 bb = *(const float4*)(cb + d0);
  float ub0[4] = {b2f(u0.x), b2f(u0.y), b2f(u0.z), b2f(u0.w)};
  float ub1[4] = {b2f(u1.x), b2f(u1.y), b2f(u1.z), b2f(u1.w)};
  float ub2[4] = {b2f(u2.x), b2f(u2.y), b2f(u2.z), b2f(u2.w)};
  float ub3[4] = {b2f(u3.x), b2f(u3.y), b2f(u3.z), b2f(u3.w)};
  float bbv[4] = {bb.x, bb.y, bb.z, bb.w};
  ushort ov[4];
#pragma unroll
  for (int j = 0; j < 4; ++j) {
    float4 wj = *(const float4*)(cw + (d0 + j) * 4);
    float acc = bbv[j];
    acc = fmaf(wj.w, ub0[j], acc);
    acc = fmaf(wj.z, ub1[j], acc);
    acc = fmaf(wj.y, ub2[j], acc);
    acc = fmaf(wj.x, ub3[j], acc);
    ov[j] = f2b(acc * sigmoidf_(acc));
  }
  ushort4 o;
  o.x = ov[0]; o.y = ov[1]; o.z = ov[2]; o.w = ov[3];
  *(ushort4*)(uc_bf + (long)r * D_INNER + d0) = o;
}

// ---------------- chunked selective scan ----------------
__global__ __launch_bounds__(256) void scan_partA(
    const ushort* __restrict__ delta_bf,
    const ushort* __restrict__ ucv_bf,
    const float* __restrict__ dbl,
    const float* __restrict__ A_log,
    float* __restrict__ hend,
    float* __restrict__ dtsum_buf)
{
  int idx = blockIdx.x * 256 + threadIdx.x;
  int d = idx & 1023;
  int c = (idx >> 10) & (CH - 1);
  int b = idx >> 15;
  float Ar[D_STATE];
#pragma unroll
  for (int s = 0; s < D_STATE; ++s) Ar[s] = -__expf(A_log[d * D_STATE + s]);
  float h[D_STATE] = {0.f};
  float dtsum = 0.f;
  const long r0 = (long)b * SEQ + c * CL;
  for (int t = 0; t < CL; ++t) {
    long r = r0 + t;
    float dt = b2f(delta_bf[r * 1024 + d]);
    float u  = b2f(ucv_bf[r * 1024 + d]);
    float du = dt * u;
    const float* bc = dbl + r * 64;
    dtsum += dt;
#pragma unroll
    for (int s = 0; s < D_STATE; ++s)
      h[s] = fmaf(h[s], __expf(dt * Ar[s]), du * bc[32 + s]);
  }
  long base = ((long)(b * CH + c) * D_STATE) * 1024 + d;
#pragma unroll
  for (int s = 0; s < D_STATE; ++s) hend[base + s * 1024] = h[s];
  dtsum_buf[(long)(b * CH + c) * 1024 + d] = dtsum;
}

__global__ __launch_bounds__(256) void scan_partB(
    float* __restrict__ hend,
    const float* __restrict__ dtsum_buf,
    const float* __restrict__ A_log)
{
  int idx = blockIdx.x * 256 + threadIdx.x;
  int d = idx & 1023;
  int s = (idx >> 10) & 15;
  int b = idx >> 14;
  float Ars = -__expf(A_log[d * D_STATE + s]);
  float H = 0.f;
  for (int c = 0; c < CH; ++c) {
    long off = ((long)(b * CH + c) * D_STATE + s) * 1024 + d;
    float he = hend[off];
    float P = __expf(Ars * dtsum_buf[(long)(b * CH + c) * 1024 + d]);
    hend[off] = H;
    H = fmaf(P, H, he);
  }
}

__global__ __launch_bounds__(256) void scan_partC(
    const ushort* __restrict__ delta_bf,
    const ushort* __restrict__ ucv_bf,
    const float* __restrict__ dbl,
    const float* __restrict__ A_log,
    const float* __restrict__ Dp,
    const ushort* __restrict__ zsilu_bf,
    const float* __restrict__ hinit,
    ushort* __restrict__ ydz_bf)          // aliases ucv_bf (elementwise)
{
  int idx = blockIdx.x * 256 + threadIdx.x;
  int d = idx & 1023;
  int c = (idx >> 10) & (CH - 1);
  int b = idx >> 15;
  float Ar[D_STATE];
#pragma unroll
  for (int s = 0; s < D_STATE; ++s) Ar[s] = -__expf(A_log[d * D_STATE + s]);
  float h[D_STATE];
  long base = ((long)(b * CH + c) * D_STATE) * 1024 + d;
#pragma unroll
  for (int s = 0; s < D_STATE; ++s) h[s] = hinit[base + s * 1024];
  float Dd = Dp[d];
  const long r0 = (long)b * SEQ + c * CL;
  for (int t = 0; t < CL; ++t) {
    long r = r0 + t;
    float dt = b2f(delta_bf[r * 1024 + d]);
    float u  = b2f(ucv_bf[r * 1024 + d]);
    float du = dt * u;
    const float* bc = dbl + r * 64;
    float y = 0.f;
#pragma unroll
    for (int s = 0; s < D_STATE; ++s) {
      h[s] = fmaf(h[s], __expf(dt * Ar[s]), du * bc[32 + s]);
      y = fmaf(h[s], bc[48 + s], y);
    }
    float zs = b2f(zsilu_bf[r * 1024 + d]);
    float yv = fmaf(u, Dd, y);
    ydz_bf[r * 1024 + d] = f2b(yv * zs);
  }
}

extern "C" void kernel_launch(void* const* d_in, const int* in_sizes, int n_in,
                              void* d_out, int out_size, void* d_ws, size_t ws_size,
                              hipStream_t stream)
{
  const float* x = (const float*)d_in[0];
  float* out = (float*)d_out;
  char* ws = (char*)d_ws;
  ushort* u_bf     = (ushort*)(ws);                     // 16 MB [8192,1024]
  ushort* zsilu_bf = (ushort*)(ws + (16u << 20));       // 16 MB
  ushort* ucv_bf   = (ushort*)(ws + (32u << 20));       // 16 MB (= ydz_bf)
  ushort* delta_bf = (ushort*)(ws + (48u << 20));       // 16 MB
  float*  dbl      = (float*)(ws + (64u << 20));        //  2 MB [8192,64]
  ushort* dblb     = (ushort*)(ws + (66u << 20));       //  1 MB
  float*  hend     = (float*)(ws + (67u << 20));        // 16 MB
  float*  dtsum    = (float*)(ws + (83u << 20));        //  1 MB
  ushort* xbf      = (ushort*)(ws + (84u << 20));       //  8 MB [8192,512]
  ushort* wbase[2];
  wbase[0] = (ushort*)(ws + (92u << 20));               //  4 MB region / dir
  wbase[1] = (ushort*)(ws + (96u << 20));
  ushort* ydz_bf = ucv_bf;

  ConvArgs ca;
  int bcur = 0;
  int si = 0;
  auto addseg = [&](const float* s, ushort* d, int nelem) {
    ca.seg[si].s = (const float4*)s; ca.seg[si].d = (ushort4*)d;
    ca.seg[si].n4 = nelem / 4; ca.seg[si].bstart = bcur;
    bcur += (nelem / 4 + 255) / 256; ++si;
  };
  addseg(x, xbf, NROWS * D_MODEL);
  for (int dir = 0; dir < 2; ++dir) {
    addseg((const float*)d_in[1 + dir * 9], wbase[dir],           2048 * 512);
    addseg((const float*)d_in[9 + dir * 9], wbase[dir] + 1048576, 512 * 1024);
    addseg((const float*)d_in[4 + dir * 9], wbase[dir] + 1572864, 64 * 1024);
    addseg((const float*)d_in[5 + dir * 9], wbase[dir] + 1638400, 1024 * 32);
  }
  dim3 blk(256);
  convert_all<<<dim3(bcur), blk, 0, stream>>>(ca);

  const int scanAC_blocks = BATCH * CH * 1024 / 256;
  const int scanB_blocks  = BATCH * 16 * 1024 / 256;

  for (int dir = 0; dir < 2; ++dir) {
    const float* cw    = (const float*)d_in[2 + dir * 9];
    const float* cb    = (const float*)d_in[3 + dir * 9];
    const float* dt_b  = (const float*)d_in[6 + dir * 9];
    const float* A_log = (const float*)d_in[7 + dir * 9];
    const float* Dp    = (const float*)d_in[8 + dir * 9];
    ushort* in_wb  = wbase[dir];
    ushort* out_wb = wbase[dir] + 1048576;
    ushort* xp_wb  = wbase[dir] + 1572864;
    ushort* dt_wb  = wbase[dir] + 1638400;

    // 1) in_proj -> u_bf + zsilu_bf (silu fused)
    gemm_bf16<128, 2, 2, 2><<<dim3(16, 64), blk, 0, stream>>>(
        xbf, D_MODEL, in_wb, D_MODEL, nullptr, u_bf, zsilu_bf,
        0, D_MODEL, nullptr, dir, 0, 0);
    // 2) conv + silu -> ucv_bf
    conv_silu<<<dim3(NROWS), blk, 0, stream>>>(u_bf, cw, cb, ucv_bf);
    // 3) x_proj -> dbl (fp32) + dblb (bf16)
    gemm_bf16<64, 4, 1, 3><<<dim3(1, 64), blk, 0, stream>>>(
        ucv_bf, D_INNER, xp_wb, D_INNER, dbl, dblb, nullptr,
        64, D_INNER, nullptr, 0, 0, 0);
    // 4) dt_proj + softplus -> delta_bf (K=32)
    gemm_bf16<128, 2, 2, 1><<<dim3(8, 64), blk, 0, stream>>>(
        dblb, 64, dt_wb, DT_RANK, nullptr, delta_bf, nullptr,
        D_INNER, DT_RANK, dt_b, 0, 0, 0);
    // 5) chunked scan
    scan_partA<<<dim3(scanAC_blocks), blk, 0, stream>>>(
        delta_bf, ucv_bf, dbl, A_log, hend, dtsum);
    scan_partB<<<dim3(scanB_blocks), blk, 0, stream>>>(hend, dtsum, A_log);
    scan_partC<<<dim3(scanAC_blocks), blk, 0, stream>>>(
        delta_bf, ucv_bf, dbl, A_log, Dp, zsilu_bf, hend, ydz_bf);
    // 6) out_proj: out (+)= ydz @ out_w.T
    gemm_bf16<128, 2, 2, 0><<<dim3(4, 64), blk, 0, stream>>>(
        ydz_bf, D_INNER, out_wb, D_INNER, out, nullptr, nullptr,
        D_MODEL, D_INNER, nullptr, 0, dir, dir);
  }
}

// Round 5
// 447.756 us; speedup vs baseline: 5.9567x; 1.0334x over previous
//
#include <hip/hip_runtime.h>
#include <math.h>

#define BATCH 8
#define SEQ 1024
#define D_MODEL 512
#define D_INNER 1024
#define D_STATE 16
#define DT_RANK 32
#define NROWS (BATCH * SEQ)   // 8192
#define CH 32
#define CL 32

typedef short short8 __attribute__((ext_vector_type(8)));
typedef float f32x4 __attribute__((ext_vector_type(4)));

__device__ __forceinline__ float sigmoidf_(float x) { return 1.f / (1.f + __expf(-x)); }

__device__ __forceinline__ ushort f2b(float f) {  // fp32 -> bf16 RNE
  uint u = __float_as_uint(f);
  return (ushort)((u + 0x7FFFu + ((u >> 16) & 1u)) >> 16);
}
__device__ __forceinline__ float b2f(ushort u) {
  return __uint_as_float(((uint)u) << 16);
}

__device__ __forceinline__ void gload16(const ushort* g, const ushort* l) {
  __builtin_amdgcn_global_load_lds(
      (const __attribute__((address_space(1))) void*)g,
      (__attribute__((address_space(3))) void*)l, 16, 0, 0);
}

// ---------------- bf16 MFMA GEMM (m97 structure + T2 chunk-swizzle + T1) ----
// C[m,n] = sum_k A[m,k]*B[n,k]; 128xBN tile, 4 waves, BK=32.
// LDS swizzle (rule #21): LDS dest linear; global SOURCE chunk pre-permuted
// (chunk ^= (row>>1)&3); read applies the same XOR. Row bases are multiples
// of 16 so the read XOR is ((lane&15)>>1)&3, uniform per lane.
// EPI: 0 = fp32 store (revC/accumC), 1 = softplus(v+bias[n]) -> bf16,
//      2 = in_proj split (n<1024 -> u bf16; n>=1024 -> silu -> zsilu bf16),
//      3 = dual store fp32 + bf16
template<int BN, int RW, int CW, int EPI>
__global__ __launch_bounds__(256) void gemm_bf16(
    const ushort* __restrict__ A, int lda,
    const ushort* __restrict__ B, int ldb,
    float* __restrict__ Cf, ushort* __restrict__ Cb, ushort* __restrict__ Cb2,
    int ldc, int K, const float* __restrict__ bias,
    int revA, int revC, int accumC)
{
  constexpr int MI = 128 / RW / 16;
  constexpr int NJ = BN / CW / 16;
  __shared__ ushort As[128 * 32];
  __shared__ ushort Bs[BN * 32];
  const int tid = threadIdx.x;
  const int w = tid >> 6, lane = tid & 63;

  // T1: bijective XCD swizzle (nwg % 8 == 0 for all our launches)
  const int nwg = gridDim.x * gridDim.y;
  int bid = blockIdx.y * gridDim.x + blockIdx.x;
  int wgid = (bid & 7) * (nwg >> 3) + (bid >> 3);
  const int bm = (wgid / gridDim.x) * 128;
  const int bn = (wgid % gridDim.x) * BN;

  const int rw0 = (w / CW) * (MI * 16);
  const int cw0 = (w % CW) * (NJ * 16);
  const int srow = w * 16 + (lane >> 2);
  // T2: pre-swizzled global source chunk
  const int scol = (((lane & 3) ^ ((lane >> 3) & 3)) << 3);
  // read-side XOR (row bases are multiples of 16)
  const int rchunk = (((lane >> 4) ^ (((lane & 15) >> 1) & 3)) << 3);

  f32x4 acc[MI][NJ] = {};

  for (int k0 = 0; k0 < K; k0 += 32) {
#pragma unroll
    for (int it = 0; it < 2; ++it) {
      int gm = bm + it * 64 + srow;
      int arow = revA ? ((gm & ~1023) | (1023 - (gm & 1023))) : gm;
      gload16(A + (long)arow * lda + k0 + scol, &As[(it * 64 + w * 16) * 32]);
    }
#pragma unroll
    for (int it = 0; it < BN / 64; ++it) {
      int gn = bn + it * 64 + srow;
      gload16(B + (long)gn * ldb + k0 + scol, &Bs[(it * 64 + w * 16) * 32]);
    }
    __syncthreads();
    short8 a[MI], b[NJ];
#pragma unroll
    for (int i = 0; i < MI; ++i)
      a[i] = *(const short8*)&As[(rw0 + i * 16 + (lane & 15)) * 32 + rchunk];
#pragma unroll
    for (int j = 0; j < NJ; ++j)
      b[j] = *(const short8*)&Bs[(cw0 + j * 16 + (lane & 15)) * 32 + rchunk];
#pragma unroll
    for (int i = 0; i < MI; ++i)
#pragma unroll
      for (int j = 0; j < NJ; ++j)
        acc[i][j] = __builtin_amdgcn_mfma_f32_16x16x32_bf16(a[i], b[j], acc[i][j], 0, 0, 0);
    __syncthreads();
  }

#pragma unroll
  for (int i = 0; i < MI; ++i)
#pragma unroll
    for (int r = 0; r < 4; ++r) {
      int m = bm + rw0 + i * 16 + (lane >> 4) * 4 + r;
      int crow = revC ? ((m & ~1023) | (1023 - (m & 1023))) : m;
#pragma unroll
      for (int j = 0; j < NJ; ++j) {
        int n = bn + cw0 + j * 16 + (lane & 15);
        float v = acc[i][j][r];
        if (EPI == 0) {
          float* p = Cf + (long)crow * ldc + n;
          if (accumC) *p += v; else *p = v;
        } else if (EPI == 1) {
          v += bias[n];
          v = (v > 20.f) ? v : log1pf(__expf(v));
          Cb[(long)crow * ldc + n] = f2b(v);
        } else if (EPI == 2) {
          if (n < D_INNER) Cb[(long)crow * D_INNER + n] = f2b(v);
          else Cb2[(long)crow * D_INNER + (n - D_INNER)] = f2b(v * sigmoidf_(v));
        } else {  // EPI == 3
          Cf[(long)crow * ldc + n] = v;
          Cb[(long)crow * ldc + n] = f2b(v);
        }
      }
    }
}

// ---------------- fused fp32->bf16 converter (x + 8 weight tensors) --------
struct Seg { const float4* s; ushort4* d; int n4; int bstart; };
struct ConvArgs { Seg seg[9]; };

__global__ __launch_bounds__(256) void convert_all(ConvArgs a)
{
  int blk = blockIdx.x;
  int i = 0;
#pragma unroll
  for (int k = 1; k < 9; ++k) if (blk >= a.seg[k].bstart) i = k;
  int idx = (blk - a.seg[i].bstart) * 256 + threadIdx.x;
  if (idx >= a.seg[i].n4) return;
  float4 v = a.seg[i].s[idx];
  ushort4 o;
  o.x = f2b(v.x); o.y = f2b(v.y); o.z = f2b(v.z); o.w = f2b(v.w);
  a.seg[i].d[idx] = o;
}

// ---------------- conv1d(k=4) + bias + silu (bf16 in/out, 4 d/thread) ------
__global__ __launch_bounds__(256) void conv_silu(
    const ushort* __restrict__ u_bf,   // [8192,1024]
    const float* __restrict__ cw,      // [1024,4]
    const float* __restrict__ cb,      // [1024]
    ushort* __restrict__ uc_bf)        // [8192,1024]
{
  int i = blockIdx.x * 256 + threadIdx.x;
  int r = i >> 8;
  int d0 = (i & 255) << 2;
  int t = r & (SEQ - 1);
  const ushort* p = u_bf + (long)r * D_INNER + d0;
  ushort4 u0 = *(const ushort4*)p;
  ushort4 u1 = (t >= 1) ? *(const ushort4*)(p - 1024) : ushort4{0, 0, 0, 0};
  ushort4 u2 = (t >= 2) ? *(const ushort4*)(p - 2048) : ushort4{0, 0, 0, 0};
  ushort4 u3 = (t >= 3) ? *(const ushort4*)(p - 3072) : ushort4{0, 0, 0, 0};
  float4 bb = *(const float4*)(cb + d0);
  float ub0[4] = {b2f(u0.x), b2f(u0.y), b2f(u0.z), b2f(u0.w)};
  float ub1[4] = {b2f(u1.x), b2f(u1.y), b2f(u1.z), b2f(u1.w)};
  float ub2[4] = {b2f(u2.x), b2f(u2.y), b2f(u2.z), b2f(u2.w)};
  float ub3[4] = {b2f(u3.x), b2f(u3.y), b2f(u3.z), b2f(u3.w)};
  float bbv[4] = {bb.x, bb.y, bb.z, bb.w};
  ushort ov[4];
#pragma unroll
  for (int j = 0; j < 4; ++j) {
    float4 wj = *(const float4*)(cw + (d0 + j) * 4);
    float acc = bbv[j];
    acc = fmaf(wj.w, ub0[j], acc);
    acc = fmaf(wj.z, ub1[j], acc);
    acc = fmaf(wj.y, ub2[j], acc);
    acc = fmaf(wj.x, ub3[j], acc);
    ov[j] = f2b(acc * sigmoidf_(acc));
  }
  ushort4 o;
  o.x = ov[0]; o.y = ov[1]; o.z = ov[2]; o.w = ov[3];
  *(ushort4*)(uc_bf + (long)r * D_INNER + d0) = o;
}

// ---------------- chunked selective scan ----------------
__global__ __launch_bounds__(256) void scan_partA(
    const ushort* __restrict__ delta_bf,
    const ushort* __restrict__ ucv_bf,
    const float* __restrict__ dbl,
    const float* __restrict__ A_log,
    float* __restrict__ hend,
    float* __restrict__ dtsum_buf)
{
  int idx = blockIdx.x * 256 + threadIdx.x;
  int d = idx & 1023;
  int c = (idx >> 10) & (CH - 1);
  int b = idx >> 15;
  float Ar[D_STATE];
#pragma unroll
  for (int s = 0; s < D_STATE; ++s) Ar[s] = -__expf(A_log[d * D_STATE + s]);
  float h[D_STATE] = {0.f};
  float dtsum = 0.f;
  const long r0 = (long)b * SEQ + c * CL;
  for (int t = 0; t < CL; ++t) {
    long r = r0 + t;
    float dt = b2f(delta_bf[r * 1024 + d]);
    float u  = b2f(ucv_bf[r * 1024 + d]);
    float du = dt * u;
    const float* bc = dbl + r * 64;
    dtsum += dt;
#pragma unroll
    for (int s = 0; s < D_STATE; ++s)
      h[s] = fmaf(h[s], __expf(dt * Ar[s]), du * bc[32 + s]);
  }
  long base = ((long)(b * CH + c) * D_STATE) * 1024 + d;
#pragma unroll
  for (int s = 0; s < D_STATE; ++s) hend[base + s * 1024] = h[s];
  dtsum_buf[(long)(b * CH + c) * 1024 + d] = dtsum;
}

__global__ __launch_bounds__(256) void scan_partB(
    float* __restrict__ hend,
    const float* __restrict__ dtsum_buf,
    const float* __restrict__ A_log)
{
  int idx = blockIdx.x * 256 + threadIdx.x;
  int d = idx & 1023;
  int s = (idx >> 10) & 15;
  int b = idx >> 14;
  float Ars = -__expf(A_log[d * D_STATE + s]);
  float H = 0.f;
  for (int c = 0; c < CH; ++c) {
    long off = ((long)(b * CH + c) * D_STATE + s) * 1024 + d;
    float he = hend[off];
    float P = __expf(Ars * dtsum_buf[(long)(b * CH + c) * 1024 + d]);
    hend[off] = H;
    H = fmaf(P, H, he);
  }
}

__global__ __launch_bounds__(256) void scan_partC(
    const ushort* __restrict__ delta_bf,
    const ushort* __restrict__ ucv_bf,
    const float* __restrict__ dbl,
    const float* __restrict__ A_log,
    const float* __restrict__ Dp,
    const ushort* __restrict__ zsilu_bf,
    const float* __restrict__ hinit,
    ushort* __restrict__ ydz_bf)          // aliases ucv_bf (elementwise)
{
  int idx = blockIdx.x * 256 + threadIdx.x;
  int d = idx & 1023;
  int c = (idx >> 10) & (CH - 1);
  int b = idx >> 15;
  float Ar[D_STATE];
#pragma unroll
  for (int s = 0; s < D_STATE; ++s) Ar[s] = -__expf(A_log[d * D_STATE + s]);
  float h[D_STATE];
  long base = ((long)(b * CH + c) * D_STATE) * 1024 + d;
#pragma unroll
  for (int s = 0; s < D_STATE; ++s) h[s] = hinit[base + s * 1024];
  float Dd = Dp[d];
  const long r0 = (long)b * SEQ + c * CL;
  for (int t = 0; t < CL; ++t) {
    long r = r0 + t;
    float dt = b2f(delta_bf[r * 1024 + d]);
    float u  = b2f(ucv_bf[r * 1024 + d]);
    float du = dt * u;
    const float* bc = dbl + r * 64;
    float y = 0.f;
#pragma unroll
    for (int s = 0; s < D_STATE; ++s) {
      h[s] = fmaf(h[s], __expf(dt * Ar[s]), du * bc[32 + s]);
      y = fmaf(h[s], bc[48 + s], y);
    }
    float zs = b2f(zsilu_bf[r * 1024 + d]);
    float yv = fmaf(u, Dd, y);
    ydz_bf[r * 1024 + d] = f2b(yv * zs);
  }
}

extern "C" void kernel_launch(void* const* d_in, const int* in_sizes, int n_in,
                              void* d_out, int out_size, void* d_ws, size_t ws_size,
                              hipStream_t stream)
{
  const float* x = (const float*)d_in[0];
  float* out = (float*)d_out;
  char* ws = (char*)d_ws;
  ushort* u_bf     = (ushort*)(ws);                     // 16 MB [8192,1024]
  ushort* zsilu_bf = (ushort*)(ws + (16u << 20));       // 16 MB
  ushort* ucv_bf   = (ushort*)(ws + (32u << 20));       // 16 MB (= ydz_bf)
  ushort* delta_bf = (ushort*)(ws + (48u << 20));       // 16 MB
  float*  dbl      = (float*)(ws + (64u << 20));        //  2 MB [8192,64]
  ushort* dblb     = (ushort*)(ws + (66u << 20));       //  1 MB
  float*  hend     = (float*)(ws + (67u << 20));        // 16 MB
  float*  dtsum    = (float*)(ws + (83u << 20));        //  1 MB
  ushort* xbf      = (ushort*)(ws + (84u << 20));       //  8 MB [8192,512]
  ushort* wbase[2];
  wbase[0] = (ushort*)(ws + (92u << 20));               //  4 MB region / dir
  wbase[1] = (ushort*)(ws + (96u << 20));
  ushort* ydz_bf = ucv_bf;

  ConvArgs ca;
  int bcur = 0;
  int si = 0;
  auto addseg = [&](const float* s, ushort* d, int nelem) {
    ca.seg[si].s = (const float4*)s; ca.seg[si].d = (ushort4*)d;
    ca.seg[si].n4 = nelem / 4; ca.seg[si].bstart = bcur;
    bcur += (nelem / 4 + 255) / 256; ++si;
  };
  addseg(x, xbf, NROWS * D_MODEL);
  for (int dir = 0; dir < 2; ++dir) {
    addseg((const float*)d_in[1 + dir * 9], wbase[dir],           2048 * 512);
    addseg((const float*)d_in[9 + dir * 9], wbase[dir] + 1048576, 512 * 1024);
    addseg((const float*)d_in[4 + dir * 9], wbase[dir] + 1572864, 64 * 1024);
    addseg((const float*)d_in[5 + dir * 9], wbase[dir] + 1638400, 1024 * 32);
  }
  dim3 blk(256);
  convert_all<<<dim3(bcur), blk, 0, stream>>>(ca);

  const int scanAC_blocks = BATCH * CH * 1024 / 256;
  const int scanB_blocks  = BATCH * 16 * 1024 / 256;

  for (int dir = 0; dir < 2; ++dir) {
    const float* cw    = (const float*)d_in[2 + dir * 9];
    const float* cb    = (const float*)d_in[3 + dir * 9];
    const float* dt_b  = (const float*)d_in[6 + dir * 9];
    const float* A_log = (const float*)d_in[7 + dir * 9];
    const float* Dp    = (const float*)d_in[8 + dir * 9];
    ushort* in_wb  = wbase[dir];
    ushort* out_wb = wbase[dir] + 1048576;
    ushort* xp_wb  = wbase[dir] + 1572864;
    ushort* dt_wb  = wbase[dir] + 1638400;

    // 1) in_proj -> u_bf + zsilu_bf (silu fused)
    gemm_bf16<128, 2, 2, 2><<<dim3(16, 64), blk, 0, stream>>>(
        xbf, D_MODEL, in_wb, D_MODEL, nullptr, u_bf, zsilu_bf,
        0, D_MODEL, nullptr, dir, 0, 0);
    // 2) conv + silu -> ucv_bf
    conv_silu<<<dim3(NROWS), blk, 0, stream>>>(u_bf, cw, cb, ucv_bf);
    // 3) x_proj -> dbl (fp32) + dblb (bf16)
    gemm_bf16<64, 4, 1, 3><<<dim3(1, 64), blk, 0, stream>>>(
        ucv_bf, D_INNER, xp_wb, D_INNER, dbl, dblb, nullptr,
        64, D_INNER, nullptr, 0, 0, 0);
    // 4) dt_proj + softplus -> delta_bf (K=32)
    gemm_bf16<128, 2, 2, 1><<<dim3(8, 64), blk, 0, stream>>>(
        dblb, 64, dt_wb, DT_RANK, nullptr, delta_bf, nullptr,
        D_INNER, DT_RANK, dt_b, 0, 0, 0);
    // 5) chunked scan
    scan_partA<<<dim3(scanAC_blocks), blk, 0, stream>>>(
        delta_bf, ucv_bf, dbl, A_log, hend, dtsum);
    scan_partB<<<dim3(scanB_blocks), blk, 0, stream>>>(hend, dtsum, A_log);
    scan_partC<<<dim3(scanAC_blocks), blk, 0, stream>>>(
        delta_bf, ucv_bf, dbl, A_log, Dp, zsilu_bf, hend, ydz_bf);
    // 6) out_proj: out (+)= ydz @ out_w.T
    gemm_bf16<128, 2, 2, 0><<<dim3(4, 64), blk, 0, stream>>>(
        ydz_bf, D_INNER, out_wb, D_INNER, out, nullptr, nullptr,
        D_MODEL, D_INNER, nullptr, 0, dir, dir);
  }
}

// Round 6
// 424.228 us; speedup vs baseline: 6.2871x; 1.0555x over previous
//
#include <hip/hip_runtime.h>
#include <math.h>

#define BATCH 8
#define SEQ 1024
#define D_MODEL 512
#define D_INNER 1024
#define D_STATE 16
#define DT_RANK 32
#define NROWS (BATCH * SEQ)   // 8192
#define CH 32
#define CL 32

typedef short short8 __attribute__((ext_vector_type(8)));
typedef float f32x4 __attribute__((ext_vector_type(4)));

__device__ __forceinline__ float sigmoidf_(float x) { return 1.f / (1.f + __expf(-x)); }

__device__ __forceinline__ ushort f2b(float f) {  // fp32 -> bf16 RNE
  uint u = __float_as_uint(f);
  return (ushort)((u + 0x7FFFu + ((u >> 16) & 1u)) >> 16);
}
__device__ __forceinline__ float b2f(ushort u) {
  return __uint_as_float(((uint)u) << 16);
}

__device__ __forceinline__ void gload16(const ushort* g, const ushort* l) {
  __builtin_amdgcn_global_load_lds(
      (const __attribute__((address_space(1))) void*)g,
      (__attribute__((address_space(3))) void*)l, 16, 0, 0);
}

// ---------------- bf16 MFMA GEMM: T3-min pipeline + T2 swizzle + T1 --------
// C[m,n] = sum_k A[m,k]*B[n,k]; 128xBN tile, 4 waves, BK=32, double-buffered
// LDS with prefetch-before-compute (one barrier per K-step).
// EPI: 0 = fp32 store (revC/accumC), 1 = softplus(v+bias[n]) -> bf16,
//      2 = in_proj split (n<1024 -> u bf16; n>=1024 -> silu -> zsilu bf16),
//      3 = dual store fp32 + bf16
template<int BN, int RW, int CW, int EPI>
__global__ __launch_bounds__(256) void gemm_bf16(
    const ushort* __restrict__ A, int lda,
    const ushort* __restrict__ B, int ldb,
    float* __restrict__ Cf, ushort* __restrict__ Cb, ushort* __restrict__ Cb2,
    int ldc, int K, const float* __restrict__ bias,
    int revA, int revC, int accumC)
{
  constexpr int MI = 128 / RW / 16;
  constexpr int NJ = BN / CW / 16;
  __shared__ ushort As[2][128 * 32];
  __shared__ ushort Bs[2][BN * 32];
  const int tid = threadIdx.x;
  const int w = tid >> 6, lane = tid & 63;

  // T1: bijective XCD swizzle (nwg % 8 == 0 for all our launches)
  const int nwg = gridDim.x * gridDim.y;
  int bid = blockIdx.y * gridDim.x + blockIdx.x;
  int wgid = (bid & 7) * (nwg >> 3) + (bid >> 3);
  const int bm = (wgid / gridDim.x) * 128;
  const int bn = (wgid % gridDim.x) * BN;

  const int rw0 = (w / CW) * (MI * 16);
  const int cw0 = (w % CW) * (NJ * 16);
  const int srow = w * 16 + (lane >> 2);
  // T2: pre-swizzled global source chunk (LDS dest stays linear, rule #21)
  const int scol = (((lane & 3) ^ ((lane >> 3) & 3)) << 3);
  // read-side XOR (fragment row bases are multiples of 16)
  const int rchunk = (((lane >> 4) ^ (((lane & 15) >> 1) & 3)) << 3);

  f32x4 acc[MI][NJ] = {};

  auto stage = [&](int buf, int k0) {
#pragma unroll
    for (int it = 0; it < 2; ++it) {
      int gm = bm + it * 64 + srow;
      int arow = revA ? ((gm & ~1023) | (1023 - (gm & 1023))) : gm;
      gload16(A + (long)arow * lda + k0 + scol, &As[buf][(it * 64 + w * 16) * 32]);
    }
#pragma unroll
    for (int it = 0; it < BN / 64; ++it) {
      int gn = bn + it * 64 + srow;
      gload16(B + (long)gn * ldb + k0 + scol, &Bs[buf][(it * 64 + w * 16) * 32]);
    }
  };

  stage(0, 0);
  __syncthreads();   // drains prologue stage

  for (int k0 = 0; k0 < K; k0 += 32) {
    int cur = (k0 >> 5) & 1;
    if (k0 + 32 < K) stage(cur ^ 1, k0 + 32);   // prefetch overlaps compute
    short8 a[MI], b[NJ];
#pragma unroll
    for (int i = 0; i < MI; ++i)
      a[i] = *(const short8*)&As[cur][(rw0 + i * 16 + (lane & 15)) * 32 + rchunk];
#pragma unroll
    for (int j = 0; j < NJ; ++j)
      b[j] = *(const short8*)&Bs[cur][(cw0 + j * 16 + (lane & 15)) * 32 + rchunk];
#pragma unroll
    for (int i = 0; i < MI; ++i)
#pragma unroll
      for (int j = 0; j < NJ; ++j)
        acc[i][j] = __builtin_amdgcn_mfma_f32_16x16x32_bf16(a[i], b[j], acc[i][j], 0, 0, 0);
    __syncthreads();   // drains prefetch (vmcnt0+lgkmcnt0) + protects dbuf reuse
  }

#pragma unroll
  for (int i = 0; i < MI; ++i)
#pragma unroll
    for (int r = 0; r < 4; ++r) {
      int m = bm + rw0 + i * 16 + (lane >> 4) * 4 + r;
      int crow = revC ? ((m & ~1023) | (1023 - (m & 1023))) : m;
#pragma unroll
      for (int j = 0; j < NJ; ++j) {
        int n = bn + cw0 + j * 16 + (lane & 15);
        float v = acc[i][j][r];
        if (EPI == 0) {
          float* p = Cf + (long)crow * ldc + n;
          if (accumC) *p += v; else *p = v;
        } else if (EPI == 1) {
          v += bias[n];
          v = (v > 20.f) ? v : log1pf(__expf(v));
          Cb[(long)crow * ldc + n] = f2b(v);
        } else if (EPI == 2) {
          if (n < D_INNER) Cb[(long)crow * D_INNER + n] = f2b(v);
          else Cb2[(long)crow * D_INNER + (n - D_INNER)] = f2b(v * sigmoidf_(v));
        } else {  // EPI == 3
          Cf[(long)crow * ldc + n] = v;
          Cb[(long)crow * ldc + n] = f2b(v);
        }
      }
    }
}

// ---------------- fused fp32->bf16 converter (x + 8 weight tensors) --------
struct Seg { const float4* s; ushort4* d; int n4; int bstart; };
struct ConvArgs { Seg seg[9]; };

__global__ __launch_bounds__(256) void convert_all(ConvArgs a)
{
  int blk = blockIdx.x;
  int i = 0;
#pragma unroll
  for (int k = 1; k < 9; ++k) if (blk >= a.seg[k].bstart) i = k;
  int idx = (blk - a.seg[i].bstart) * 256 + threadIdx.x;
  if (idx >= a.seg[i].n4) return;
  float4 v = a.seg[i].s[idx];
  ushort4 o;
  o.x = f2b(v.x); o.y = f2b(v.y); o.z = f2b(v.z); o.w = f2b(v.w);
  a.seg[i].d[idx] = o;
}

// ---------------- conv1d(k=4) + bias + silu (bf16 in/out, 4 d/thread) ------
__global__ __launch_bounds__(256) void conv_silu(
    const ushort* __restrict__ u_bf,   // [8192,1024]
    const float* __restrict__ cw,      // [1024,4]
    const float* __restrict__ cb,      // [1024]
    ushort* __restrict__ uc_bf)        // [8192,1024]
{
  int i = blockIdx.x * 256 + threadIdx.x;
  int r = i >> 8;
  int d0 = (i & 255) << 2;
  int t = r & (SEQ - 1);
  const ushort* p = u_bf + (long)r * D_INNER + d0;
  ushort4 u0 = *(const ushort4*)p;
  ushort4 u1 = (t >= 1) ? *(const ushort4*)(p - 1024) : ushort4{0, 0, 0, 0};
  ushort4 u2 = (t >= 2) ? *(const ushort4*)(p - 2048) : ushort4{0, 0, 0, 0};
  ushort4 u3 = (t >= 3) ? *(const ushort4*)(p - 3072) : ushort4{0, 0, 0, 0};
  float4 bb = *(const float4*)(cb + d0);
  float ub0[4] = {b2f(u0.x), b2f(u0.y), b2f(u0.z), b2f(u0.w)};
  float ub1[4] = {b2f(u1.x), b2f(u1.y), b2f(u1.z), b2f(u1.w)};
  float ub2[4] = {b2f(u2.x), b2f(u2.y), b2f(u2.z), b2f(u2.w)};
  float ub3[4] = {b2f(u3.x), b2f(u3.y), b2f(u3.z), b2f(u3.w)};
  float bbv[4] = {bb.x, bb.y, bb.z, bb.w};
  ushort ov[4];
#pragma unroll
  for (int j = 0; j < 4; ++j) {
    float4 wj = *(const float4*)(cw + (d0 + j) * 4);
    float acc = bbv[j];
    acc = fmaf(wj.w, ub0[j], acc);
    acc = fmaf(wj.z, ub1[j], acc);
    acc = fmaf(wj.y, ub2[j], acc);
    acc = fmaf(wj.x, ub3[j], acc);
    ov[j] = f2b(acc * sigmoidf_(acc));
  }
  ushort4 o;
  o.x = ov[0]; o.y = ov[1]; o.z = ov[2]; o.w = ov[3];
  *(ushort4*)(uc_bf + (long)r * D_INNER + d0) = o;
}

// Compute decay powers E^(s+1), s=0..15, from E = exp(-dt). Log-depth muls.
#define EP_FAST(dt, Ep)                                        \
  {                                                            \
    float E1 = __expf(-(dt));                                  \
    float E2 = E1 * E1, E4 = E2 * E2, E8 = E4 * E4;            \
    Ep[0] = E1;  Ep[1] = E2;      Ep[2] = E2 * E1;             \
    Ep[3] = E4;  Ep[4] = E4 * E1; Ep[5] = E4 * E2;             \
    Ep[6] = E4 * Ep[2]; Ep[7] = E8;  Ep[8] = E8 * E1;          \
    Ep[9] = E8 * E2; Ep[10] = E8 * Ep[2]; Ep[11] = E8 * E4;    \
    Ep[12] = E8 * Ep[4]; Ep[13] = E8 * Ep[5];                  \
    Ep[14] = E8 * Ep[6]; Ep[15] = E8 * E8;                     \
  }

// fast-path validity: A[s] == -(s+1) (A_log = log(arange(1,17)) per spec);
// verified at runtime per thread, generic fallback otherwise.
__device__ __forceinline__ bool a_is_arange(const float* Ar) {
  bool ok = true;
#pragma unroll
  for (int s = 0; s < D_STATE; ++s)
    ok = ok && (fabsf(Ar[s] + (float)(s + 1)) <= 1e-3f * (float)(s + 1));
  return ok;
}

// ---------------- chunked selective scan ----------------
__global__ __launch_bounds__(256) void scan_partA(
    const ushort* __restrict__ delta_bf,
    const ushort* __restrict__ ucv_bf,
    const float* __restrict__ dbl,
    const float* __restrict__ A_log,
    float* __restrict__ hend,
    float* __restrict__ dtsum_buf)
{
  int idx = blockIdx.x * 256 + threadIdx.x;
  int d = idx & 1023;
  int c = (idx >> 10) & (CH - 1);
  int b = idx >> 15;
  float Ar[D_STATE];
#pragma unroll
  for (int s = 0; s < D_STATE; ++s) Ar[s] = -__expf(A_log[d * D_STATE + s]);
  const bool fast = a_is_arange(Ar);
  float h[D_STATE] = {0.f};
  float dtsum = 0.f;
  const long r0 = (long)b * SEQ + c * CL;

  if (fast) {
    for (int t = 0; t < CL; ++t) {
      long r = r0 + t;
      float dt = b2f(delta_bf[r * 1024 + d]);
      float u  = b2f(ucv_bf[r * 1024 + d]);
      float du = dt * u;
      dtsum += dt;
      const float4* bp = (const float4*)(dbl + r * 64 + 32);
      float4 B0 = bp[0], B1 = bp[1], B2 = bp[2], B3 = bp[3];
      float Bv[16] = {B0.x, B0.y, B0.z, B0.w, B1.x, B1.y, B1.z, B1.w,
                      B2.x, B2.y, B2.z, B2.w, B3.x, B3.y, B3.z, B3.w};
      float Ep[16];
      EP_FAST(dt, Ep);
#pragma unroll
      for (int s = 0; s < D_STATE; ++s)
        h[s] = fmaf(h[s], Ep[s], du * Bv[s]);
    }
  } else {
    for (int t = 0; t < CL; ++t) {
      long r = r0 + t;
      float dt = b2f(delta_bf[r * 1024 + d]);
      float u  = b2f(ucv_bf[r * 1024 + d]);
      float du = dt * u;
      dtsum += dt;
      const float4* bp = (const float4*)(dbl + r * 64 + 32);
      float4 B0 = bp[0], B1 = bp[1], B2 = bp[2], B3 = bp[3];
      float Bv[16] = {B0.x, B0.y, B0.z, B0.w, B1.x, B1.y, B1.z, B1.w,
                      B2.x, B2.y, B2.z, B2.w, B3.x, B3.y, B3.z, B3.w};
#pragma unroll
      for (int s = 0; s < D_STATE; ++s)
        h[s] = fmaf(h[s], __expf(dt * Ar[s]), du * Bv[s]);
    }
  }
  long base = ((long)(b * CH + c) * D_STATE) * 1024 + d;
#pragma unroll
  for (int s = 0; s < D_STATE; ++s) hend[base + s * 1024] = h[s];
  dtsum_buf[(long)(b * CH + c) * 1024 + d] = dtsum;
}

__global__ __launch_bounds__(256) void scan_partB(
    float* __restrict__ hend,
    const float* __restrict__ dtsum_buf,
    const float* __restrict__ A_log)
{
  int idx = blockIdx.x * 256 + threadIdx.x;
  int d = idx & 1023;
  int s = (idx >> 10) & 15;
  int b = idx >> 14;
  float Ars = -__expf(A_log[d * D_STATE + s]);
  float H = 0.f;
  for (int c = 0; c < CH; ++c) {
    long off = ((long)(b * CH + c) * D_STATE + s) * 1024 + d;
    float he = hend[off];
    float P = __expf(Ars * dtsum_buf[(long)(b * CH + c) * 1024 + d]);
    hend[off] = H;
    H = fmaf(P, H, he);
  }
}

__global__ __launch_bounds__(256) void scan_partC(
    const ushort* __restrict__ delta_bf,
    const ushort* __restrict__ ucv_bf,
    const float* __restrict__ dbl,
    const float* __restrict__ A_log,
    const float* __restrict__ Dp,
    const ushort* __restrict__ zsilu_bf,
    const float* __restrict__ hinit,
    ushort* __restrict__ ydz_bf)          // aliases ucv_bf (elementwise)
{
  int idx = blockIdx.x * 256 + threadIdx.x;
  int d = idx & 1023;
  int c = (idx >> 10) & (CH - 1);
  int b = idx >> 15;
  float Ar[D_STATE];
#pragma unroll
  for (int s = 0; s < D_STATE; ++s) Ar[s] = -__expf(A_log[d * D_STATE + s]);
  const bool fast = a_is_arange(Ar);
  float h[D_STATE];
  long base = ((long)(b * CH + c) * D_STATE) * 1024 + d;
#pragma unroll
  for (int s = 0; s < D_STATE; ++s) h[s] = hinit[base + s * 1024];
  float Dd = Dp[d];
  const long r0 = (long)b * SEQ + c * CL;

  if (fast) {
    for (int t = 0; t < CL; ++t) {
      long r = r0 + t;
      float dt = b2f(delta_bf[r * 1024 + d]);
      float u  = b2f(ucv_bf[r * 1024 + d]);
      float du = dt * u;
      const float4* bp = (const float4*)(dbl + r * 64 + 32);
      float4 B0 = bp[0], B1 = bp[1], B2 = bp[2], B3 = bp[3];
      float4 C0 = bp[4], C1 = bp[5], C2 = bp[6], C3 = bp[7];
      float Bv[16] = {B0.x, B0.y, B0.z, B0.w, B1.x, B1.y, B1.z, B1.w,
                      B2.x, B2.y, B2.z, B2.w, B3.x, B3.y, B3.z, B3.w};
      float Cv[16] = {C0.x, C0.y, C0.z, C0.w, C1.x, C1.y, C1.z, C1.w,
                      C2.x, C2.y, C2.z, C2.w, C3.x, C3.y, C3.z, C3.w};
      float Ep[16];
      EP_FAST(dt, Ep);
      float y = 0.f;
#pragma unroll
      for (int s = 0; s < D_STATE; ++s) {
        h[s] = fmaf(h[s], Ep[s], du * Bv[s]);
        y = fmaf(h[s], Cv[s], y);
      }
      float zs = b2f(zsilu_bf[r * 1024 + d]);
      float yv = fmaf(u, Dd, y);
      ydz_bf[r * 1024 + d] = f2b(yv * zs);
    }
  } else {
    for (int t = 0; t < CL; ++t) {
      long r = r0 + t;
      float dt = b2f(delta_bf[r * 1024 + d]);
      float u  = b2f(ucv_bf[r * 1024 + d]);
      float du = dt * u;
      const float4* bp = (const float4*)(dbl + r * 64 + 32);
      float4 B0 = bp[0], B1 = bp[1], B2 = bp[2], B3 = bp[3];
      float4 C0 = bp[4], C1 = bp[5], C2 = bp[6], C3 = bp[7];
      float Bv[16] = {B0.x, B0.y, B0.z, B0.w, B1.x, B1.y, B1.z, B1.w,
                      B2.x, B2.y, B2.z, B2.w, B3.x, B3.y, B3.z, B3.w};
      float Cv[16] = {C0.x, C0.y, C0.z, C0.w, C1.x, C1.y, C1.z, C1.w,
                      C2.x, C2.y, C2.z, C2.w, C3.x, C3.y, C3.z, C3.w};
      float y = 0.f;
#pragma unroll
      for (int s = 0; s < D_STATE; ++s) {
        h[s] = fmaf(h[s], __expf(dt * Ar[s]), du * Bv[s]);
        y = fmaf(h[s], Cv[s], y);
      }
      float zs = b2f(zsilu_bf[r * 1024 + d]);
      float yv = fmaf(u, Dd, y);
      ydz_bf[r * 1024 + d] = f2b(yv * zs);
    }
  }
}

extern "C" void kernel_launch(void* const* d_in, const int* in_sizes, int n_in,
                              void* d_out, int out_size, void* d_ws, size_t ws_size,
                              hipStream_t stream)
{
  const float* x = (const float*)d_in[0];
  float* out = (float*)d_out;
  char* ws = (char*)d_ws;
  ushort* u_bf     = (ushort*)(ws);                     // 16 MB [8192,1024]
  ushort* zsilu_bf = (ushort*)(ws + (16u << 20));       // 16 MB
  ushort* ucv_bf   = (ushort*)(ws + (32u << 20));       // 16 MB (= ydz_bf)
  ushort* delta_bf = (ushort*)(ws + (48u << 20));       // 16 MB
  float*  dbl      = (float*)(ws + (64u << 20));        //  2 MB [8192,64]
  ushort* dblb     = (ushort*)(ws + (66u << 20));       //  1 MB
  float*  hend     = (float*)(ws + (67u << 20));        // 16 MB
  float*  dtsum    = (float*)(ws + (83u << 20));        //  1 MB
  ushort* xbf      = (ushort*)(ws + (84u << 20));       //  8 MB [8192,512]
  ushort* wbase[2];
  wbase[0] = (ushort*)(ws + (92u << 20));               //  4 MB region / dir
  wbase[1] = (ushort*)(ws + (96u << 20));
  ushort* ydz_bf = ucv_bf;

  ConvArgs ca;
  int bcur = 0;
  int si = 0;
  auto addseg = [&](const float* s, ushort* d, int nelem) {
    ca.seg[si].s = (const float4*)s; ca.seg[si].d = (ushort4*)d;
    ca.seg[si].n4 = nelem / 4; ca.seg[si].bstart = bcur;
    bcur += (nelem / 4 + 255) / 256; ++si;
  };
  addseg(x, xbf, NROWS * D_MODEL);
  for (int dir = 0; dir < 2; ++dir) {
    addseg((const float*)d_in[1 + dir * 9], wbase[dir],           2048 * 512);
    addseg((const float*)d_in[9 + dir * 9], wbase[dir] + 1048576, 512 * 1024);
    addseg((const float*)d_in[4 + dir * 9], wbase[dir] + 1572864, 64 * 1024);
    addseg((const float*)d_in[5 + dir * 9], wbase[dir] + 1638400, 1024 * 32);
  }
  dim3 blk(256);
  convert_all<<<dim3(bcur), blk, 0, stream>>>(ca);

  const int scanAC_blocks = BATCH * CH * 1024 / 256;
  const int scanB_blocks  = BATCH * 16 * 1024 / 256;

  for (int dir = 0; dir < 2; ++dir) {
    const float* cw    = (const float*)d_in[2 + dir * 9];
    const float* cb    = (const float*)d_in[3 + dir * 9];
    const float* dt_b  = (const float*)d_in[6 + dir * 9];
    const float* A_log = (const float*)d_in[7 + dir * 9];
    const float* Dp    = (const float*)d_in[8 + dir * 9];
    ushort* in_wb  = wbase[dir];
    ushort* out_wb = wbase[dir] + 1048576;
    ushort* xp_wb  = wbase[dir] + 1572864;
    ushort* dt_wb  = wbase[dir] + 1638400;

    // 1) in_proj -> u_bf + zsilu_bf (silu fused)
    gemm_bf16<128, 2, 2, 2><<<dim3(16, 64), blk, 0, stream>>>(
        xbf, D_MODEL, in_wb, D_MODEL, nullptr, u_bf, zsilu_bf,
        0, D_MODEL, nullptr, dir, 0, 0);
    // 2) conv + silu -> ucv_bf
    conv_silu<<<dim3(NROWS), blk, 0, stream>>>(u_bf, cw, cb, ucv_bf);
    // 3) x_proj -> dbl (fp32) + dblb (bf16)
    gemm_bf16<64, 4, 1, 3><<<dim3(1, 64), blk, 0, stream>>>(
        ucv_bf, D_INNER, xp_wb, D_INNER, dbl, dblb, nullptr,
        64, D_INNER, nullptr, 0, 0, 0);
    // 4) dt_proj + softplus -> delta_bf (K=32)
    gemm_bf16<128, 2, 2, 1><<<dim3(8, 64), blk, 0, stream>>>(
        dblb, 64, dt_wb, DT_RANK, nullptr, delta_bf, nullptr,
        D_INNER, DT_RANK, dt_b, 0, 0, 0);
    // 5) chunked scan
    scan_partA<<<dim3(scanAC_blocks), blk, 0, stream>>>(
        delta_bf, ucv_bf, dbl, A_log, hend, dtsum);
    scan_partB<<<dim3(scanB_blocks), blk, 0, stream>>>(hend, dtsum, A_log);
    scan_partC<<<dim3(scanAC_blocks), blk, 0, stream>>>(
        delta_bf, ucv_bf, dbl, A_log, Dp, zsilu_bf, hend, ydz_bf);
    // 6) out_proj: out (+)= ydz @ out_w.T
    gemm_bf16<128, 2, 2, 0><<<dim3(4, 64), blk, 0, stream>>>(
        ydz_bf, D_INNER, out_wb, D_INNER, out, nullptr, nullptr,
        D_MODEL, D_INNER, nullptr, 0, dir, dir);
  }
}

// Round 7
// 392.371 us; speedup vs baseline: 6.7976x; 1.0812x over previous
//
#include <hip/hip_runtime.h>
#include <math.h>

#define BATCH 8
#define SEQ 1024
#define D_MODEL 512
#define D_INNER 1024
#define D_STATE 16
#define DT_RANK 32
#define NROWS (BATCH * SEQ)   // 8192
#define CH 64                 // chunks per sequence
#define CL 16                 // chunk length

typedef short short8 __attribute__((ext_vector_type(8)));
typedef float f32x4 __attribute__((ext_vector_type(4)));

__device__ __forceinline__ float sigmoidf_(float x) { return 1.f / (1.f + __expf(-x)); }

__device__ __forceinline__ ushort f2b(float f) {  // fp32 -> bf16 RNE
  uint u = __float_as_uint(f);
  return (ushort)((u + 0x7FFFu + ((u >> 16) & 1u)) >> 16);
}
__device__ __forceinline__ float b2f(ushort u) {
  return __uint_as_float(((uint)u) << 16);
}

__device__ __forceinline__ void gload16(const ushort* g, const ushort* l) {
  __builtin_amdgcn_global_load_lds(
      (const __attribute__((address_space(1))) void*)g,
      (__attribute__((address_space(3))) void*)l, 16, 0, 0);
}

// ---------------- bf16 MFMA GEMM: T3-min pipeline + T2 swizzle + T1 --------
template<int BN, int RW, int CW, int EPI>
__global__ __launch_bounds__(256) void gemm_bf16(
    const ushort* __restrict__ A, int lda,
    const ushort* __restrict__ B, int ldb,
    float* __restrict__ Cf, ushort* __restrict__ Cb, ushort* __restrict__ Cb2,
    int ldc, int K, const float* __restrict__ bias,
    int revA, int revC, int accumC)
{
  constexpr int MI = 128 / RW / 16;
  constexpr int NJ = BN / CW / 16;
  __shared__ ushort As[2][128 * 32];
  __shared__ ushort Bs[2][BN * 32];
  const int tid = threadIdx.x;
  const int w = tid >> 6, lane = tid & 63;

  const int nwg = gridDim.x * gridDim.y;
  int bid = blockIdx.y * gridDim.x + blockIdx.x;
  int wgid = (bid & 7) * (nwg >> 3) + (bid >> 3);
  const int bm = (wgid / gridDim.x) * 128;
  const int bn = (wgid % gridDim.x) * BN;

  const int rw0 = (w / CW) * (MI * 16);
  const int cw0 = (w % CW) * (NJ * 16);
  const int srow = w * 16 + (lane >> 2);
  const int scol = (((lane & 3) ^ ((lane >> 3) & 3)) << 3);
  const int rchunk = (((lane >> 4) ^ (((lane & 15) >> 1) & 3)) << 3);

  f32x4 acc[MI][NJ] = {};

  auto stage = [&](int buf, int k0) {
#pragma unroll
    for (int it = 0; it < 2; ++it) {
      int gm = bm + it * 64 + srow;
      int arow = revA ? ((gm & ~1023) | (1023 - (gm & 1023))) : gm;
      gload16(A + (long)arow * lda + k0 + scol, &As[buf][(it * 64 + w * 16) * 32]);
    }
#pragma unroll
    for (int it = 0; it < BN / 64; ++it) {
      int gn = bn + it * 64 + srow;
      gload16(B + (long)gn * ldb + k0 + scol, &Bs[buf][(it * 64 + w * 16) * 32]);
    }
  };

  stage(0, 0);
  __syncthreads();

  for (int k0 = 0; k0 < K; k0 += 32) {
    int cur = (k0 >> 5) & 1;
    if (k0 + 32 < K) stage(cur ^ 1, k0 + 32);
    short8 a[MI], b[NJ];
#pragma unroll
    for (int i = 0; i < MI; ++i)
      a[i] = *(const short8*)&As[cur][(rw0 + i * 16 + (lane & 15)) * 32 + rchunk];
#pragma unroll
    for (int j = 0; j < NJ; ++j)
      b[j] = *(const short8*)&Bs[cur][(cw0 + j * 16 + (lane & 15)) * 32 + rchunk];
#pragma unroll
    for (int i = 0; i < MI; ++i)
#pragma unroll
      for (int j = 0; j < NJ; ++j)
        acc[i][j] = __builtin_amdgcn_mfma_f32_16x16x32_bf16(a[i], b[j], acc[i][j], 0, 0, 0);
    __syncthreads();
  }

#pragma unroll
  for (int i = 0; i < MI; ++i)
#pragma unroll
    for (int r = 0; r < 4; ++r) {
      int m = bm + rw0 + i * 16 + (lane >> 4) * 4 + r;
      int crow = revC ? ((m & ~1023) | (1023 - (m & 1023))) : m;
#pragma unroll
      for (int j = 0; j < NJ; ++j) {
        int n = bn + cw0 + j * 16 + (lane & 15);
        float v = acc[i][j][r];
        if (EPI == 0) {
          float* p = Cf + (long)crow * ldc + n;
          if (accumC) *p += v; else *p = v;
        } else if (EPI == 1) {
          v += bias[n];
          v = (v > 20.f) ? v : log1pf(__expf(v));
          Cb[(long)crow * ldc + n] = f2b(v);
        } else if (EPI == 2) {
          if (n < D_INNER) Cb[(long)crow * D_INNER + n] = f2b(v);
          else Cb2[(long)crow * D_INNER + (n - D_INNER)] = f2b(v * sigmoidf_(v));
        } else {  // EPI == 3
          Cf[(long)crow * ldc + n] = v;
          Cb[(long)crow * ldc + n] = f2b(v);
        }
      }
    }
}

// ---------------- fused fp32->bf16 converter (x + 8 weight tensors) --------
struct Seg { const float4* s; ushort4* d; int n4; int bstart; };
struct ConvArgs { Seg seg[9]; };

__global__ __launch_bounds__(256) void convert_all(ConvArgs a)
{
  int blk = blockIdx.x;
  int i = 0;
#pragma unroll
  for (int k = 1; k < 9; ++k) if (blk >= a.seg[k].bstart) i = k;
  int idx = (blk - a.seg[i].bstart) * 256 + threadIdx.x;
  if (idx >= a.seg[i].n4) return;
  float4 v = a.seg[i].s[idx];
  ushort4 o;
  o.x = f2b(v.x); o.y = f2b(v.y); o.z = f2b(v.z); o.w = f2b(v.w);
  a.seg[i].d[idx] = o;
}

// ---------------- conv1d(k=4) + bias + silu (bf16 in/out, 4 d/thread) ------
__global__ __launch_bounds__(256) void conv_silu(
    const ushort* __restrict__ u_bf,
    const float* __restrict__ cw,
    const float* __restrict__ cb,
    ushort* __restrict__ uc_bf)
{
  int i = blockIdx.x * 256 + threadIdx.x;
  int r = i >> 8;
  int d0 = (i & 255) << 2;
  int t = r & (SEQ - 1);
  const ushort* p = u_bf + (long)r * D_INNER + d0;
  ushort4 u0 = *(const ushort4*)p;
  ushort4 u1 = (t >= 1) ? *(const ushort4*)(p - 1024) : ushort4{0, 0, 0, 0};
  ushort4 u2 = (t >= 2) ? *(const ushort4*)(p - 2048) : ushort4{0, 0, 0, 0};
  ushort4 u3 = (t >= 3) ? *(const ushort4*)(p - 3072) : ushort4{0, 0, 0, 0};
  float4 bb = *(const float4*)(cb + d0);
  float ub0[4] = {b2f(u0.x), b2f(u0.y), b2f(u0.z), b2f(u0.w)};
  float ub1[4] = {b2f(u1.x), b2f(u1.y), b2f(u1.z), b2f(u1.w)};
  float ub2[4] = {b2f(u2.x), b2f(u2.y), b2f(u2.z), b2f(u2.w)};
  float ub3[4] = {b2f(u3.x), b2f(u3.y), b2f(u3.z), b2f(u3.w)};
  float bbv[4] = {bb.x, bb.y, bb.z, bb.w};
  ushort ov[4];
#pragma unroll
  for (int j = 0; j < 4; ++j) {
    float4 wj = *(const float4*)(cw + (d0 + j) * 4);
    float acc = bbv[j];
    acc = fmaf(wj.w, ub0[j], acc);
    acc = fmaf(wj.z, ub1[j], acc);
    acc = fmaf(wj.y, ub2[j], acc);
    acc = fmaf(wj.x, ub3[j], acc);
    ov[j] = f2b(acc * sigmoidf_(acc));
  }
  ushort4 o;
  o.x = ov[0]; o.y = ov[1]; o.z = ov[2]; o.w = ov[3];
  *(ushort4*)(uc_bf + (long)r * D_INNER + d0) = o;
}

// Decay powers E^(s+1), s=0..15, from E = exp(-dt).
#define EP_FAST(dt, Ep)                                        \
  {                                                            \
    float E1 = __expf(-(dt));                                  \
    float E2 = E1 * E1, E4 = E2 * E2, E8 = E4 * E4;            \
    Ep[0] = E1;  Ep[1] = E2;      Ep[2] = E2 * E1;             \
    Ep[3] = E4;  Ep[4] = E4 * E1; Ep[5] = E4 * E2;             \
    Ep[6] = E4 * Ep[2]; Ep[7] = E8;  Ep[8] = E8 * E1;          \
    Ep[9] = E8 * E2; Ep[10] = E8 * Ep[2]; Ep[11] = E8 * E4;    \
    Ep[12] = E8 * Ep[4]; Ep[13] = E8 * Ep[5];                  \
    Ep[14] = E8 * Ep[6]; Ep[15] = E8 * E8;                     \
  }

__device__ __forceinline__ bool a_is_arange(const float* Ar) {
  bool ok = true;
#pragma unroll
  for (int s = 0; s < D_STATE; ++s)
    ok = ok && (fabsf(Ar[s] + (float)(s + 1)) <= 1e-3f * (float)(s + 1));
  return ok;
}

// ---------------- chunked selective scan ----------------
// Block = 256 consecutive d, same (b, chunk). B/C rows staged in LDS.
__global__ __launch_bounds__(256) void scan_partA(
    const ushort* __restrict__ delta_bf,
    const ushort* __restrict__ ucv_bf,
    const float* __restrict__ dbl,
    const float* __restrict__ A_log,
    float* __restrict__ hend,          // [8][CH][16][1024]
    float* __restrict__ dtsum_buf)     // [8][CH][1024]
{
  __shared__ float bc[CL][32];         // cols 32..63 of dbl (B|C)
  int idx = blockIdx.x * 256 + threadIdx.x;
  int d = idx & 1023;
  int c = (idx >> 10) & (CH - 1);
  int b = idx >> 16;
  const long r0 = (long)b * SEQ + c * CL;
  {
    int tt = threadIdx.x >> 4, cc = (threadIdx.x & 15) * 2;
    *(float2*)&bc[tt][cc] = *(const float2*)&dbl[(r0 + tt) * 64 + 32 + cc];
  }
  float Ar[D_STATE];
#pragma unroll
  for (int s = 0; s < D_STATE; ++s) Ar[s] = -__expf(A_log[d * D_STATE + s]);
  const bool fast = a_is_arange(Ar);
  float h[D_STATE] = {0.f};
  float dtsum = 0.f;
  __syncthreads();

  if (fast) {
    for (int t = 0; t < CL; ++t) {
      long r = r0 + t;
      float dt = b2f(delta_bf[r * 1024 + d]);
      float u  = b2f(ucv_bf[r * 1024 + d]);
      float du = dt * u;
      dtsum += dt;
      float Ep[16];
      EP_FAST(dt, Ep);
#pragma unroll
      for (int s = 0; s < D_STATE; ++s)
        h[s] = fmaf(h[s], Ep[s], du * bc[t][s]);
    }
  } else {
    for (int t = 0; t < CL; ++t) {
      long r = r0 + t;
      float dt = b2f(delta_bf[r * 1024 + d]);
      float u  = b2f(ucv_bf[r * 1024 + d]);
      float du = dt * u;
      dtsum += dt;
#pragma unroll
      for (int s = 0; s < D_STATE; ++s)
        h[s] = fmaf(h[s], __expf(dt * Ar[s]), du * bc[t][s]);
    }
  }
  long base = ((long)(b * CH + c) * D_STATE) * 1024 + d;
#pragma unroll
  for (int s = 0; s < D_STATE; ++s) hend[base + s * 1024] = h[s];
  dtsum_buf[(long)(b * CH + c) * 1024 + d] = dtsum;
}

__global__ __launch_bounds__(256) void scan_partB(
    float* __restrict__ hend,
    const float* __restrict__ dtsum_buf,
    const float* __restrict__ A_log)
{
  int idx = blockIdx.x * 256 + threadIdx.x;
  int d = idx & 1023;
  int s = (idx >> 10) & 15;
  int b = idx >> 14;
  float Ars = -__expf(A_log[d * D_STATE + s]);
  float H = 0.f;
  for (int c = 0; c < CH; ++c) {
    long off = ((long)(b * CH + c) * D_STATE + s) * 1024 + d;
    float he = hend[off];
    float P = __expf(Ars * dtsum_buf[(long)(b * CH + c) * 1024 + d]);
    hend[off] = H;
    H = fmaf(P, H, he);
  }
}

__global__ __launch_bounds__(256) void scan_partC(
    const ushort* __restrict__ delta_bf,
    const ushort* __restrict__ ucv_bf,
    const float* __restrict__ dbl,
    const float* __restrict__ A_log,
    const float* __restrict__ Dp,
    const ushort* __restrict__ zsilu_bf,
    const float* __restrict__ hinit,
    ushort* __restrict__ ydz_bf)          // aliases ucv_bf (elementwise)
{
  __shared__ float bc[CL][32];
  int idx = blockIdx.x * 256 + threadIdx.x;
  int d = idx & 1023;
  int c = (idx >> 10) & (CH - 1);
  int b = idx >> 16;
  const long r0 = (long)b * SEQ + c * CL;
  {
    int tt = threadIdx.x >> 4, cc = (threadIdx.x & 15) * 2;
    *(float2*)&bc[tt][cc] = *(const float2*)&dbl[(r0 + tt) * 64 + 32 + cc];
  }
  float Ar[D_STATE];
#pragma unroll
  for (int s = 0; s < D_STATE; ++s) Ar[s] = -__expf(A_log[d * D_STATE + s]);
  const bool fast = a_is_arange(Ar);
  float h[D_STATE];
  long base = ((long)(b * CH + c) * D_STATE) * 1024 + d;
#pragma unroll
  for (int s = 0; s < D_STATE; ++s) h[s] = hinit[base + s * 1024];
  float Dd = Dp[d];
  __syncthreads();

  if (fast) {
    for (int t = 0; t < CL; ++t) {
      long r = r0 + t;
      float dt = b2f(delta_bf[r * 1024 + d]);
      float u  = b2f(ucv_bf[r * 1024 + d]);
      float du = dt * u;
      float Ep[16];
      EP_FAST(dt, Ep);
      float y = 0.f;
#pragma unroll
      for (int s = 0; s < D_STATE; ++s) {
        h[s] = fmaf(h[s], Ep[s], du * bc[t][s]);
        y = fmaf(h[s], bc[t][16 + s], y);
      }
      float zs = b2f(zsilu_bf[r * 1024 + d]);
      float yv = fmaf(u, Dd, y);
      ydz_bf[r * 1024 + d] = f2b(yv * zs);
    }
  } else {
    for (int t = 0; t < CL; ++t) {
      long r = r0 + t;
      float dt = b2f(delta_bf[r * 1024 + d]);
      float u  = b2f(ucv_bf[r * 1024 + d]);
      float du = dt * u;
      float y = 0.f;
#pragma unroll
      for (int s = 0; s < D_STATE; ++s) {
        h[s] = fmaf(h[s], __expf(dt * Ar[s]), du * bc[t][s]);
        y = fmaf(h[s], bc[t][16 + s], y);
      }
      float zs = b2f(zsilu_bf[r * 1024 + d]);
      float yv = fmaf(u, Dd, y);
      ydz_bf[r * 1024 + d] = f2b(yv * zs);
    }
  }
}

extern "C" void kernel_launch(void* const* d_in, const int* in_sizes, int n_in,
                              void* d_out, int out_size, void* d_ws, size_t ws_size,
                              hipStream_t stream)
{
  const float* x = (const float*)d_in[0];
  float* out = (float*)d_out;
  char* ws = (char*)d_ws;
  ushort* u_bf     = (ushort*)(ws);                     // 16 MB [8192,1024]
  ushort* zsilu_bf = (ushort*)(ws + (16u << 20));       // 16 MB
  ushort* ucv_bf   = (ushort*)(ws + (32u << 20));       // 16 MB (= ydz_bf)
  ushort* delta_bf = (ushort*)(ws + (48u << 20));       // 16 MB
  float*  dbl      = (float*)(ws + (64u << 20));        //  2 MB [8192,64]
  ushort* dblb     = (ushort*)(ws + (66u << 20));       //  1 MB
  float*  hend     = (float*)(ws + (67u << 20));        // 32 MB [8][CH][16][1024]
  float*  dtsum    = (float*)(ws + (99u << 20));        //  2 MB [8][CH][1024]
  ushort* xbf      = (ushort*)(ws + (101u << 20));      //  8 MB [8192,512]
  ushort* wbase[2];
  wbase[0] = (ushort*)(ws + (109u << 20));              //  4 MB region / dir
  wbase[1] = (ushort*)(ws + (113u << 20));
  ushort* ydz_bf = ucv_bf;

  ConvArgs ca;
  int bcur = 0;
  int si = 0;
  auto addseg = [&](const float* s, ushort* d, int nelem) {
    ca.seg[si].s = (const float4*)s; ca.seg[si].d = (ushort4*)d;
    ca.seg[si].n4 = nelem / 4; ca.seg[si].bstart = bcur;
    bcur += (nelem / 4 + 255) / 256; ++si;
  };
  addseg(x, xbf, NROWS * D_MODEL);
  for (int dir = 0; dir < 2; ++dir) {
    addseg((const float*)d_in[1 + dir * 9], wbase[dir],           2048 * 512);
    addseg((const float*)d_in[9 + dir * 9], wbase[dir] + 1048576, 512 * 1024);
    addseg((const float*)d_in[4 + dir * 9], wbase[dir] + 1572864, 64 * 1024);
    addseg((const float*)d_in[5 + dir * 9], wbase[dir] + 1638400, 1024 * 32);
  }
  dim3 blk(256);
  convert_all<<<dim3(bcur), blk, 0, stream>>>(ca);

  const int scanAC_blocks = BATCH * CH * 1024 / 256;   // 2048
  const int scanB_blocks  = BATCH * 16 * 1024 / 256;   // 512

  for (int dir = 0; dir < 2; ++dir) {
    const float* cw    = (const float*)d_in[2 + dir * 9];
    const float* cb    = (const float*)d_in[3 + dir * 9];
    const float* dt_b  = (const float*)d_in[6 + dir * 9];
    const float* A_log = (const float*)d_in[7 + dir * 9];
    const float* Dp    = (const float*)d_in[8 + dir * 9];
    ushort* in_wb  = wbase[dir];
    ushort* out_wb = wbase[dir] + 1048576;
    ushort* xp_wb  = wbase[dir] + 1572864;
    ushort* dt_wb  = wbase[dir] + 1638400;

    // 1) in_proj -> u_bf + zsilu_bf (silu fused)
    gemm_bf16<128, 2, 2, 2><<<dim3(16, 64), blk, 0, stream>>>(
        xbf, D_MODEL, in_wb, D_MODEL, nullptr, u_bf, zsilu_bf,
        0, D_MODEL, nullptr, dir, 0, 0);
    // 2) conv + silu -> ucv_bf
    conv_silu<<<dim3(NROWS), blk, 0, stream>>>(u_bf, cw, cb, ucv_bf);
    // 3) x_proj -> dbl (fp32) + dblb (bf16)
    gemm_bf16<64, 4, 1, 3><<<dim3(1, 64), blk, 0, stream>>>(
        ucv_bf, D_INNER, xp_wb, D_INNER, dbl, dblb, nullptr,
        64, D_INNER, nullptr, 0, 0, 0);
    // 4) dt_proj + softplus -> delta_bf (K=32)
    gemm_bf16<128, 2, 2, 1><<<dim3(8, 64), blk, 0, stream>>>(
        dblb, 64, dt_wb, DT_RANK, nullptr, delta_bf, nullptr,
        D_INNER, DT_RANK, dt_b, 0, 0, 0);
    // 5) chunked scan
    scan_partA<<<dim3(scanAC_blocks), blk, 0, stream>>>(
        delta_bf, ucv_bf, dbl, A_log, hend, dtsum);
    scan_partB<<<dim3(scanB_blocks), blk, 0, stream>>>(hend, dtsum, A_log);
    scan_partC<<<dim3(scanAC_blocks), blk, 0, stream>>>(
        delta_bf, ucv_bf, dbl, A_log, Dp, zsilu_bf, hend, ydz_bf);
    // 6) out_proj: out (+)= ydz @ out_w.T
    gemm_bf16<128, 2, 2, 0><<<dim3(4, 64), blk, 0, stream>>>(
        ydz_bf, D_INNER, out_wb, D_INNER, out, nullptr, nullptr,
        D_MODEL, D_INNER, nullptr, 0, dir, dir);
  }
}

// Round 8
// 341.563 us; speedup vs baseline: 7.8087x; 1.1488x over previous
//
#include <hip/hip_runtime.h>
#include <math.h>

#define BATCH 8
#define SEQ 1024
#define D_MODEL 512
#define D_INNER 1024
#define D_STATE 16
#define DT_RANK 32
#define NROWS (BATCH * SEQ)   // 8192
#define CH 64                 // chunks per sequence
#define CL 16                 // chunk length
#define USLAB 8388608l        // 8192*1024 elems (one dir slab)

typedef short short8 __attribute__((ext_vector_type(8)));
typedef float f32x4 __attribute__((ext_vector_type(4)));

__device__ __forceinline__ float sigmoidf_(float x) { return 1.f / (1.f + __expf(-x)); }

__device__ __forceinline__ ushort f2b(float f) {  // fp32 -> bf16 RNE
  uint u = __float_as_uint(f);
  return (ushort)((u + 0x7FFFu + ((u >> 16) & 1u)) >> 16);
}
__device__ __forceinline__ float b2f(ushort u) {
  return __uint_as_float(((uint)u) << 16);
}

__device__ __forceinline__ void gload16(const ushort* g, const ushort* l) {
  __builtin_amdgcn_global_load_lds(
      (const __attribute__((address_space(1))) void*)g,
      (__attribute__((address_space(3))) void*)l, 16, 0, 0);
}

__device__ __forceinline__ int revrow(int m) {
  return (m & ~1023) | (1023 - (m & 1023));
}

// ---------------- bf16 MFMA GEMM: 2-phase dbuf + T2 swizzle + T1 -----------
// C[m,n] = sum_k A[m,k]*B[n,k]; 128xBN tile, 4 waves, BK=32.
// EPI: 0 = fp32 store (revC/accumC)
//      1 = softplus(v+bias[n]) -> Cb bf16
//      2 = merged in_proj: n -> {dir, u|z}; bwd rows reversed; z gets silu
//      4 = plain bf16 -> Cb
template<int BN, int RW, int CW, int EPI>
__global__ __launch_bounds__(256) void gemm_bf16(
    const ushort* __restrict__ A, int lda,
    const ushort* __restrict__ B, int ldb,
    float* __restrict__ Cf, ushort* __restrict__ Cb, ushort* __restrict__ Cb2,
    int ldc, int K, const float* __restrict__ bias,
    int revC, int accumC)
{
  constexpr int MI = 128 / RW / 16;
  constexpr int NJ = BN / CW / 16;
  __shared__ ushort As[2][128 * 32];
  __shared__ ushort Bs[2][BN * 32];
  const int tid = threadIdx.x;
  const int w = tid >> 6, lane = tid & 63;

  const int nwg = gridDim.x * gridDim.y;
  int bid = blockIdx.y * gridDim.x + blockIdx.x;
  int wgid = (bid & 7) * (nwg >> 3) + (bid >> 3);
  const int bm = (wgid / gridDim.x) * 128;
  const int bn = (wgid % gridDim.x) * BN;

  const int rw0 = (w / CW) * (MI * 16);
  const int cw0 = (w % CW) * (NJ * 16);
  const int srow = w * 16 + (lane >> 2);
  const int scol = (((lane & 3) ^ ((lane >> 3) & 3)) << 3);
  const int rchunk = (((lane >> 4) ^ (((lane & 15) >> 1) & 3)) << 3);

  f32x4 acc[MI][NJ] = {};

  auto stage = [&](int buf, int k0) {
#pragma unroll
    for (int it = 0; it < 2; ++it) {
      int gm = bm + it * 64 + srow;
      gload16(A + (long)gm * lda + k0 + scol, &As[buf][(it * 64 + w * 16) * 32]);
    }
#pragma unroll
    for (int it = 0; it < BN / 64; ++it) {
      int gn = bn + it * 64 + srow;
      gload16(B + (long)gn * ldb + k0 + scol, &Bs[buf][(it * 64 + w * 16) * 32]);
    }
  };

  stage(0, 0);
  __syncthreads();

  for (int k0 = 0; k0 < K; k0 += 32) {
    int cur = (k0 >> 5) & 1;
    if (k0 + 32 < K) stage(cur ^ 1, k0 + 32);
    short8 a[MI], b[NJ];
#pragma unroll
    for (int i = 0; i < MI; ++i)
      a[i] = *(const short8*)&As[cur][(rw0 + i * 16 + (lane & 15)) * 32 + rchunk];
#pragma unroll
    for (int j = 0; j < NJ; ++j)
      b[j] = *(const short8*)&Bs[cur][(cw0 + j * 16 + (lane & 15)) * 32 + rchunk];
#pragma unroll
    for (int i = 0; i < MI; ++i)
#pragma unroll
      for (int j = 0; j < NJ; ++j)
        acc[i][j] = __builtin_amdgcn_mfma_f32_16x16x32_bf16(a[i], b[j], acc[i][j], 0, 0, 0);
    __syncthreads();
  }

#pragma unroll
  for (int i = 0; i < MI; ++i)
#pragma unroll
    for (int r = 0; r < 4; ++r) {
      int m = bm + rw0 + i * 16 + (lane >> 4) * 4 + r;
      int crow = revC ? revrow(m) : m;
#pragma unroll
      for (int j = 0; j < NJ; ++j) {
        int n = bn + cw0 + j * 16 + (lane & 15);
        float v = acc[i][j][r];
        if (EPI == 0) {
          float* p = Cf + (long)crow * ldc + n;
          if (accumC) *p += v; else *p = v;
        } else if (EPI == 1) {
          v += bias[n];
          v = (v > 20.f) ? v : log1pf(__expf(v));
          Cb[(long)crow * ldc + n] = f2b(v);
        } else if (EPI == 2) {
          int dir = n >> 11;          // 0 = fwd, 1 = bwd
          int nn = n & 2047;          // within-dir col
          int sub = nn & 1023;
          int row = dir ? revrow(m) : m;
          if (nn < D_INNER)
            Cb[dir * USLAB + (long)row * 1024 + sub] = f2b(v);
          else
            Cb2[dir * USLAB + (long)row * 1024 + sub] = f2b(v * sigmoidf_(v));
        } else {  // EPI == 4
          Cb[(long)crow * ldc + n] = f2b(v);
        }
      }
    }
}

// ---------------- fused fp32->bf16 converter (x + 8 weight tensors) --------
struct Seg { const float4* s; ushort4* d; int n4; int bstart; };
struct ConvArgs { Seg seg[9]; };

__global__ __launch_bounds__(256) void convert_all(ConvArgs a)
{
  int blk = blockIdx.x;
  int i = 0;
#pragma unroll
  for (int k = 1; k < 9; ++k) if (blk >= a.seg[k].bstart) i = k;
  int idx = (blk - a.seg[i].bstart) * 256 + threadIdx.x;
  if (idx >= a.seg[i].n4) return;
  float4 v = a.seg[i].s[idx];
  ushort4 o;
  o.x = f2b(v.x); o.y = f2b(v.y); o.z = f2b(v.z); o.w = f2b(v.w);
  a.seg[i].d[idx] = o;
}

// ------------- conv1d(k=4) + bias + silu, both dirs (4 d/thread) -----------
__global__ __launch_bounds__(256) void conv_silu(
    const ushort* __restrict__ u_bf,   // [2][8192][1024]
    const float* __restrict__ cw_f, const float* __restrict__ cw_b,
    const float* __restrict__ cb_f, const float* __restrict__ cb_b,
    ushort* __restrict__ uc_bf)        // [2][8192][1024]
{
  long i = (long)blockIdx.x * 256 + threadIdx.x;
  int dir = (int)(i >> 21);
  int r = (int)(i >> 8) & 8191;
  int d0 = ((int)i & 255) << 2;
  int t = r & (SEQ - 1);
  const float* cw = dir ? cw_b : cw_f;
  const float* cb = dir ? cb_b : cb_f;
  const ushort* p = u_bf + dir * USLAB + (long)r * D_INNER + d0;
  ushort4 u0 = *(const ushort4*)p;
  ushort4 u1 = (t >= 1) ? *(const ushort4*)(p - 1024) : ushort4{0, 0, 0, 0};
  ushort4 u2 = (t >= 2) ? *(const ushort4*)(p - 2048) : ushort4{0, 0, 0, 0};
  ushort4 u3 = (t >= 3) ? *(const ushort4*)(p - 3072) : ushort4{0, 0, 0, 0};
  float4 bb = *(const float4*)(cb + d0);
  float ub0[4] = {b2f(u0.x), b2f(u0.y), b2f(u0.z), b2f(u0.w)};
  float ub1[4] = {b2f(u1.x), b2f(u1.y), b2f(u1.z), b2f(u1.w)};
  float ub2[4] = {b2f(u2.x), b2f(u2.y), b2f(u2.z), b2f(u2.w)};
  float ub3[4] = {b2f(u3.x), b2f(u3.y), b2f(u3.z), b2f(u3.w)};
  float bbv[4] = {bb.x, bb.y, bb.z, bb.w};
  ushort ov[4];
#pragma unroll
  for (int j = 0; j < 4; ++j) {
    float4 wj = *(const float4*)(cw + (d0 + j) * 4);
    float acc = bbv[j];
    acc = fmaf(wj.w, ub0[j], acc);
    acc = fmaf(wj.z, ub1[j], acc);
    acc = fmaf(wj.y, ub2[j], acc);
    acc = fmaf(wj.x, ub3[j], acc);
    ov[j] = f2b(acc * sigmoidf_(acc));
  }
  ushort4 o;
  o.x = ov[0]; o.y = ov[1]; o.z = ov[2]; o.w = ov[3];
  *(ushort4*)(uc_bf + dir * USLAB + (long)r * D_INNER + d0) = o;
}

// Decay powers E^(s+1), s=0..15, from E = exp(-dt).
#define EP_FAST(dt, Ep)                                        \
  {                                                            \
    float E1 = __expf(-(dt));                                  \
    float E2 = E1 * E1, E4 = E2 * E2, E8 = E4 * E4;            \
    Ep[0] = E1;  Ep[1] = E2;      Ep[2] = E2 * E1;             \
    Ep[3] = E4;  Ep[4] = E4 * E1; Ep[5] = E4 * E2;             \
    Ep[6] = E4 * Ep[2]; Ep[7] = E8;  Ep[8] = E8 * E1;          \
    Ep[9] = E8 * E2; Ep[10] = E8 * Ep[2]; Ep[11] = E8 * E4;    \
    Ep[12] = E8 * Ep[4]; Ep[13] = E8 * Ep[5];                  \
    Ep[14] = E8 * Ep[6]; Ep[15] = E8 * E8;                     \
  }

__device__ __forceinline__ bool a_is_arange(const float* Ar) {
  bool ok = true;
#pragma unroll
  for (int s = 0; s < D_STATE; ++s)
    ok = ok && (fabsf(Ar[s] + (float)(s + 1)) <= 1e-3f * (float)(s + 1));
  return ok;
}

// ---------------- chunked selective scan (both dirs in one grid) -----------
// idx bits: d[0:10) c[10:16) b[16:19) dir[19]
__global__ __launch_bounds__(256) void scan_partA(
    const ushort* __restrict__ delta_bf,  // [2][8192][1024]
    const ushort* __restrict__ ucv_bf,    // [2][8192][1024]
    const ushort* __restrict__ dblb,      // [2][8192][64]
    const float* __restrict__ A_log_f, const float* __restrict__ A_log_b,
    ushort* __restrict__ hend,            // [2][8][CH][16][1024] bf16
    float* __restrict__ dtsum_buf)        // [2][8][CH][1024]
{
  __shared__ float bc[CL][16];            // B rows of this chunk
  long idx = (long)blockIdx.x * 256 + threadIdx.x;
  int d = (int)idx & 1023;
  int c = ((int)idx >> 10) & (CH - 1);
  int b = ((int)idx >> 16) & 7;
  int dir = (int)(idx >> 19);
  const long r0 = (long)b * SEQ + c * CL;
  const ushort* dblp = dblb + (long)dir * NROWS * 64;
  {
    int tt = threadIdx.x >> 4, ss = threadIdx.x & 15;
    bc[tt][ss] = b2f(dblp[(r0 + tt) * 64 + 32 + ss]);
  }
  const float* Alog = dir ? A_log_b : A_log_f;
  const ushort* dp = delta_bf + dir * USLAB;
  const ushort* up = ucv_bf + dir * USLAB;
  float Ar[D_STATE];
#pragma unroll
  for (int s = 0; s < D_STATE; ++s) Ar[s] = -__expf(Alog[d * D_STATE + s]);
  const bool fast = a_is_arange(Ar);
  float h[D_STATE] = {0.f};
  float dtsum = 0.f;
  __syncthreads();

  if (fast) {
    for (int t = 0; t < CL; ++t) {
      long r = r0 + t;
      float dt = b2f(dp[r * 1024 + d]);
      float u  = b2f(up[r * 1024 + d]);
      float du = dt * u;
      dtsum += dt;
      float Ep[16];
      EP_FAST(dt, Ep);
#pragma unroll
      for (int s = 0; s < D_STATE; ++s)
        h[s] = fmaf(h[s], Ep[s], du * bc[t][s]);
    }
  } else {
    for (int t = 0; t < CL; ++t) {
      long r = r0 + t;
      float dt = b2f(dp[r * 1024 + d]);
      float u  = b2f(up[r * 1024 + d]);
      float du = dt * u;
      dtsum += dt;
#pragma unroll
      for (int s = 0; s < D_STATE; ++s)
        h[s] = fmaf(h[s], __expf(dt * Ar[s]), du * bc[t][s]);
    }
  }
  long base = ((long)((dir * 8 + b) * CH + c) * D_STATE) * 1024 + d;
#pragma unroll
  for (int s = 0; s < D_STATE; ++s) hend[base + s * 1024] = f2b(h[s]);
  dtsum_buf[(long)((dir * 8 + b) * CH + c) * 1024 + d] = dtsum;
}

// idx bits: d[0:10) s[10:14) b[14:17) dir[17]
__global__ __launch_bounds__(256) void scan_partB(
    ushort* __restrict__ hend,
    const float* __restrict__ dtsum_buf,
    const float* __restrict__ A_log_f, const float* __restrict__ A_log_b)
{
  long idx = (long)blockIdx.x * 256 + threadIdx.x;
  int d = (int)idx & 1023;
  int s = ((int)idx >> 10) & 15;
  int b = ((int)idx >> 14) & 7;
  int dir = (int)(idx >> 17);
  const float* Alog = dir ? A_log_b : A_log_f;
  float Ars = -__expf(Alog[d * D_STATE + s]);
  float H = 0.f;
  for (int c = 0; c < CH; ++c) {
    long off = ((long)((dir * 8 + b) * CH + c) * D_STATE + s) * 1024 + d;
    float he = b2f(hend[off]);
    float P = __expf(Ars * dtsum_buf[(long)((dir * 8 + b) * CH + c) * 1024 + d]);
    hend[off] = f2b(H);
    H = fmaf(P, H, he);
  }
}

__global__ __launch_bounds__(256) void scan_partC(
    const ushort* __restrict__ delta_bf,
    const ushort* __restrict__ ucv_bf,
    const ushort* __restrict__ dblb,
    const float* __restrict__ A_log_f, const float* __restrict__ A_log_b,
    const float* __restrict__ Dp_f, const float* __restrict__ Dp_b,
    const ushort* __restrict__ zsilu_bf,
    const ushort* __restrict__ hinit,
    ushort* __restrict__ ydz_bf)          // elementwise alias of ucv_bf
{
  __shared__ float bc[CL][32];
  long idx = (long)blockIdx.x * 256 + threadIdx.x;
  int d = (int)idx & 1023;
  int c = ((int)idx >> 10) & (CH - 1);
  int b = ((int)idx >> 16) & 7;
  int dir = (int)(idx >> 19);
  const long r0 = (long)b * SEQ + c * CL;
  const ushort* dblp = dblb + (long)dir * NROWS * 64;
  {
    int tt = threadIdx.x >> 4, cc = (threadIdx.x & 15) * 2;
    ushort2 v = *(const ushort2*)&dblp[(r0 + tt) * 64 + 32 + cc];
    bc[tt][cc] = b2f(v.x); bc[tt][cc + 1] = b2f(v.y);
  }
  const float* Alog = dir ? A_log_b : A_log_f;
  const ushort* dp = delta_bf + dir * USLAB;
  const ushort* up = ucv_bf + dir * USLAB;
  const ushort* zp = zsilu_bf + dir * USLAB;
  ushort* yp = ydz_bf + dir * USLAB;
  float Ar[D_STATE];
#pragma unroll
  for (int s = 0; s < D_STATE; ++s) Ar[s] = -__expf(Alog[d * D_STATE + s]);
  const bool fast = a_is_arange(Ar);
  float h[D_STATE];
  long base = ((long)((dir * 8 + b) * CH + c) * D_STATE) * 1024 + d;
#pragma unroll
  for (int s = 0; s < D_STATE; ++s) h[s] = b2f(hinit[base + s * 1024]);
  float Dd = (dir ? Dp_b : Dp_f)[d];
  __syncthreads();

  if (fast) {
    for (int t = 0; t < CL; ++t) {
      long r = r0 + t;
      float dt = b2f(dp[r * 1024 + d]);
      float u  = b2f(up[r * 1024 + d]);
      float du = dt * u;
      float Ep[16];
      EP_FAST(dt, Ep);
      float y = 0.f;
#pragma unroll
      for (int s = 0; s < D_STATE; ++s) {
        h[s] = fmaf(h[s], Ep[s], du * bc[t][s]);
        y = fmaf(h[s], bc[t][16 + s], y);
      }
      float zs = b2f(zp[r * 1024 + d]);
      float yv = fmaf(u, Dd, y);
      yp[r * 1024 + d] = f2b(yv * zs);
    }
  } else {
    for (int t = 0; t < CL; ++t) {
      long r = r0 + t;
      float dt = b2f(dp[r * 1024 + d]);
      float u  = b2f(up[r * 1024 + d]);
      float du = dt * u;
      float y = 0.f;
#pragma unroll
      for (int s = 0; s < D_STATE; ++s) {
        h[s] = fmaf(h[s], __expf(dt * Ar[s]), du * bc[t][s]);
        y = fmaf(h[s], bc[t][16 + s], y);
      }
      float zs = b2f(zp[r * 1024 + d]);
      float yv = fmaf(u, Dd, y);
      yp[r * 1024 + d] = f2b(yv * zs);
    }
  }
}

extern "C" void kernel_launch(void* const* d_in, const int* in_sizes, int n_in,
                              void* d_out, int out_size, void* d_ws, size_t ws_size,
                              hipStream_t stream)
{
  const float* x = (const float*)d_in[0];
  float* out = (float*)d_out;
  char* ws = (char*)d_ws;
  // Layout (MiB offsets), total 136 MiB:
  ushort* zsilu  = (ushort*)(ws);                     // 32: [2][8192][1024]
  ushort* ucv    = (ushort*)(ws + (32ul << 20));      // 32: [2][8192][1024] (=ydz)
  ushort* u_bf   = (ushort*)(ws + (64ul << 20));      // 32: [2][8192][1024] (=delta)
  ushort* hend   = (ushort*)(ws + (96ul << 20));      // 32: [2][8][CH][16][1024] bf16
  float*  dtsum  = (float*)(ws + (128ul << 20));      //  4: [2][8][CH][1024]
  ushort* dblb   = (ushort*)(ws + (132ul << 20));     //  2: [2][8192][64]
  ushort* out_wb = (ushort*)(ws + (134ul << 20));     //  2: [2][512][1024]
  // transient aliases inside hend slab (dead before scan_partA writes hend):
  ushort* xbf    = hend;                              //  8: [8192][512]
  ushort* in_wb  = hend + (8ul << 19);                //  4: [4096][512]  (8 MiB in)
  ushort* xp_wb  = hend + (12ul << 19);               // .25: [2][64][1024]
  ushort* dt_wb  = xp_wb + 131072;                    // .125: [2][1024][32]
  ushort* delta  = u_bf;
  ushort* ydz    = ucv;

  ConvArgs ca;
  int bcur = 0, si = 0;
  auto addseg = [&](const float* s, ushort* d, int nelem) {
    ca.seg[si].s = (const float4*)s; ca.seg[si].d = (ushort4*)d;
    ca.seg[si].n4 = nelem / 4; ca.seg[si].bstart = bcur;
    bcur += (nelem / 4 + 255) / 256; ++si;
  };
  addseg(x, xbf, NROWS * D_MODEL);
  addseg((const float*)d_in[1], in_wb, 2048 * 512);           // in_w_f
  addseg((const float*)d_in[10], in_wb + 2048 * 512, 2048 * 512); // in_w_b
  addseg((const float*)d_in[9], out_wb, 512 * 1024);          // out_w_f
  addseg((const float*)d_in[18], out_wb + 512 * 1024, 512 * 1024);
  addseg((const float*)d_in[4], xp_wb, 64 * 1024);            // xp_w_f
  addseg((const float*)d_in[13], xp_wb + 65536, 64 * 1024);
  addseg((const float*)d_in[5], dt_wb, 1024 * 32);            // dt_w_f
  addseg((const float*)d_in[14], dt_wb + 32768, 1024 * 32);

  dim3 blk(256);
  convert_all<<<dim3(bcur), blk, 0, stream>>>(ca);

  // 1) merged in_proj: [8192,4096] -> u/zsilu per dir (bwd rows reversed)
  gemm_bf16<128, 2, 2, 2><<<dim3(32, 64), blk, 0, stream>>>(
      xbf, D_MODEL, in_wb, D_MODEL, nullptr, u_bf, zsilu,
      0, D_MODEL, nullptr, 0, 0);
  // 2) conv + silu, both dirs
  conv_silu<<<dim3(2 * NROWS), blk, 0, stream>>>(
      u_bf, (const float*)d_in[2], (const float*)d_in[11],
      (const float*)d_in[3], (const float*)d_in[12], ucv);
  // 3) x_proj per dir -> dblb
  for (int dir = 0; dir < 2; ++dir)
    gemm_bf16<64, 4, 1, 4><<<dim3(1, 64), blk, 0, stream>>>(
        ucv + dir * USLAB, D_INNER, xp_wb + dir * 65536, D_INNER,
        nullptr, dblb + dir * NROWS * 64, nullptr, 64, D_INNER, nullptr, 0, 0);
  // 4) dt_proj + softplus per dir -> delta (over u slab)
  for (int dir = 0; dir < 2; ++dir)
    gemm_bf16<128, 2, 2, 1><<<dim3(8, 64), blk, 0, stream>>>(
        dblb + dir * NROWS * 64, 64, dt_wb + dir * 32768, DT_RANK,
        nullptr, delta + dir * USLAB, nullptr, D_INNER, DT_RANK,
        (const float*)d_in[6 + dir * 9], 0, 0);
  // 5) chunked scan, both dirs
  const float* Alf = (const float*)d_in[7];
  const float* Alb = (const float*)d_in[16];
  scan_partA<<<dim3(2 * BATCH * CH * 1024 / 256), blk, 0, stream>>>(
      delta, ucv, dblb, Alf, Alb, hend, dtsum);
  scan_partB<<<dim3(2 * BATCH * 16 * 1024 / 256), blk, 0, stream>>>(
      hend, dtsum, Alf, Alb);
  scan_partC<<<dim3(2 * BATCH * CH * 1024 / 256), blk, 0, stream>>>(
      delta, ucv, dblb, Alf, Alb,
      (const float*)d_in[8], (const float*)d_in[17], zsilu, hend, ydz);
  // 6) out_proj per dir (bwd: reversed rows + accumulate)
  for (int dir = 0; dir < 2; ++dir)
    gemm_bf16<128, 2, 2, 0><<<dim3(4, 64), blk, 0, stream>>>(
        ydz + dir * USLAB, D_INNER, out_wb + dir * 512 * 1024, D_INNER,
        out, nullptr, nullptr, D_MODEL, D_INNER, nullptr, dir, dir);
}

// Round 9
// 300.710 us; speedup vs baseline: 8.8696x; 1.1359x over previous
//
#include <hip/hip_runtime.h>
#include <math.h>

#define BATCH 8
#define SEQ 1024
#define D_MODEL 512
#define D_INNER 1024
#define D_STATE 16
#define DT_RANK 32
#define NROWS (BATCH * SEQ)   // 8192
#define CH 64                 // chunks per sequence
#define CL 16                 // chunk length
#define USLAB 8388608l        // 8192*1024 elems (one dir slab)

typedef short short8 __attribute__((ext_vector_type(8)));
typedef float f32x4 __attribute__((ext_vector_type(4)));

__device__ __forceinline__ float sigmoidf_(float x) { return 1.f / (1.f + __expf(-x)); }

__device__ __forceinline__ ushort f2b(float f) {  // fp32 -> bf16 RNE
  uint u = __float_as_uint(f);
  return (ushort)((u + 0x7FFFu + ((u >> 16) & 1u)) >> 16);
}
__device__ __forceinline__ float b2f(ushort u) {
  return __uint_as_float(((uint)u) << 16);
}

__device__ __forceinline__ void gload16(const ushort* g, const ushort* l) {
  __builtin_amdgcn_global_load_lds(
      (const __attribute__((address_space(1))) void*)g,
      (__attribute__((address_space(3))) void*)l, 16, 0, 0);
}

__device__ __forceinline__ int revrow(int m) {
  return (m & ~1023) | (1023 - (m & 1023));
}

// ---------------- bf16 MFMA GEMM: 2-phase dbuf + T2 swizzle + T1 -----------
// C[m,n] = sum_k A[m,k]*B[n,k]; BMxBN tile, 4 waves, BK=32.
// EPI: 0 = fp32 store (revC/accumC)
//      1 = softplus(v+bias[n]) -> Cb bf16
//      2 = merged in_proj: n -> {dir, u|z}; bwd rows reversed; z gets silu
//      4 = plain bf16 -> Cb
// DUALK: K spans two slabs; for k0 >= K/2 use A2 (rows reversed) and B2.
//        lda/ldb are PER-SLAB row strides.
// MDIAG: block-diagonal over M: rows >= 8192 use B + b_stride, bias2.
template<int BM, int BN, int RW, int CW, int EPI, int DUALK, int MDIAG>
__global__ __launch_bounds__(256) void gemm_bf16(
    const ushort* __restrict__ A, int lda, const ushort* __restrict__ A2,
    const ushort* __restrict__ B, int ldb, const ushort* __restrict__ B2,
    float* __restrict__ Cf, ushort* __restrict__ Cb, ushort* __restrict__ Cb2,
    int ldc, int K, const float* __restrict__ bias, const float* __restrict__ bias2,
    int b_stride, int revC, int accumC)
{
  constexpr int MI = BM / RW / 16;
  constexpr int NJ = BN / CW / 16;
  __shared__ ushort As[2][BM * 32];
  __shared__ ushort Bs[2][BN * 32];
  const int tid = threadIdx.x;
  const int w = tid >> 6, lane = tid & 63;

  const int nwg = gridDim.x * gridDim.y;
  int bid = blockIdx.y * gridDim.x + blockIdx.x;
  int wgid = (bid & 7) * (nwg >> 3) + (bid >> 3);
  const int bm = (wgid / gridDim.x) * BM;
  const int bn = (wgid % gridDim.x) * BN;

  if (MDIAG) {
    int mdir = (bm >= NROWS) ? 1 : 0;
    B += mdir * b_stride;
    if (mdir) bias = bias2;
  }

  const int rw0 = (w / CW) * (MI * 16);
  const int cw0 = (w % CW) * (NJ * 16);
  const int srow = w * 16 + (lane >> 2);
  const int scol = (((lane & 3) ^ ((lane >> 3) & 3)) << 3);
  const int rchunk = (((lane >> 4) ^ (((lane & 15) >> 1) & 3)) << 3);

  f32x4 acc[MI][NJ] = {};

  auto stage = [&](int buf, int k0) {
    const ushort* Ap = A;
    const ushort* Bp = B;
    int kc = k0;
    bool hi = false;
    if (DUALK && k0 >= (K >> 1)) { Ap = A2; Bp = B2; kc = k0 - (K >> 1); hi = true; }
#pragma unroll
    for (int it = 0; it < BM / 64; ++it) {
      int gm = bm + it * 64 + srow;
      int arow = (DUALK && hi) ? revrow(gm) : gm;
      gload16(Ap + (long)arow * lda + kc + scol, &As[buf][(it * 64 + w * 16) * 32]);
    }
#pragma unroll
    for (int it = 0; it < BN / 64; ++it) {
      int gn = bn + it * 64 + srow;
      gload16(Bp + (long)gn * ldb + kc + scol, &Bs[buf][(it * 64 + w * 16) * 32]);
    }
  };

  stage(0, 0);
  __syncthreads();

  for (int k0 = 0; k0 < K; k0 += 32) {
    int cur = (k0 >> 5) & 1;
    if (k0 + 32 < K) stage(cur ^ 1, k0 + 32);
    short8 a[MI], b[NJ];
#pragma unroll
    for (int i = 0; i < MI; ++i)
      a[i] = *(const short8*)&As[cur][(rw0 + i * 16 + (lane & 15)) * 32 + rchunk];
#pragma unroll
    for (int j = 0; j < NJ; ++j)
      b[j] = *(const short8*)&Bs[cur][(cw0 + j * 16 + (lane & 15)) * 32 + rchunk];
#pragma unroll
    for (int i = 0; i < MI; ++i)
#pragma unroll
      for (int j = 0; j < NJ; ++j)
        acc[i][j] = __builtin_amdgcn_mfma_f32_16x16x32_bf16(a[i], b[j], acc[i][j], 0, 0, 0);
    __syncthreads();
  }

#pragma unroll
  for (int i = 0; i < MI; ++i)
#pragma unroll
    for (int r = 0; r < 4; ++r) {
      int m = bm + rw0 + i * 16 + (lane >> 4) * 4 + r;
      int crow = revC ? revrow(m) : m;
#pragma unroll
      for (int j = 0; j < NJ; ++j) {
        int n = bn + cw0 + j * 16 + (lane & 15);
        float v = acc[i][j][r];
        if (EPI == 0) {
          float* p = Cf + (long)crow * ldc + n;
          if (accumC) *p += v; else *p = v;
        } else if (EPI == 1) {
          v += bias[n];
          v = (v > 20.f) ? v : log1pf(__expf(v));
          Cb[(long)crow * ldc + n] = f2b(v);
        } else if (EPI == 2) {
          int dir = n >> 11;          // 0 = fwd, 1 = bwd
          int nn = n & 2047;          // within-dir col
          int sub = nn & 1023;
          int row = dir ? revrow(m) : m;
          if (nn < D_INNER)
            Cb[dir * USLAB + (long)row * 1024 + sub] = f2b(v);
          else
            Cb2[dir * USLAB + (long)row * 1024 + sub] = f2b(v * sigmoidf_(v));
        } else {  // EPI == 4
          Cb[(long)crow * ldc + n] = f2b(v);
        }
      }
    }
}

// ---------------- fused fp32->bf16 converter (x + 8 weight tensors) --------
struct Seg { const float4* s; ushort4* d; int n4; int bstart; };
struct ConvArgs { Seg seg[9]; };

__global__ __launch_bounds__(256) void convert_all(ConvArgs a)
{
  int blk = blockIdx.x;
  int i = 0;
#pragma unroll
  for (int k = 1; k < 9; ++k) if (blk >= a.seg[k].bstart) i = k;
  int idx = (blk - a.seg[i].bstart) * 256 + threadIdx.x;
  if (idx >= a.seg[i].n4) return;
  float4 v = a.seg[i].s[idx];
  ushort4 o;
  o.x = f2b(v.x); o.y = f2b(v.y); o.z = f2b(v.z); o.w = f2b(v.w);
  a.seg[i].d[idx] = o;
}

// ------------- conv1d(k=4) + bias + silu, both dirs (4 d/thread) -----------
__global__ __launch_bounds__(256) void conv_silu(
    const ushort* __restrict__ u_bf,   // [2][8192][1024]
    const float* __restrict__ cw_f, const float* __restrict__ cw_b,
    const float* __restrict__ cb_f, const float* __restrict__ cb_b,
    ushort* __restrict__ uc_bf)        // [2][8192][1024]
{
  long i = (long)blockIdx.x * 256 + threadIdx.x;
  int dir = (int)(i >> 21);
  int r = (int)(i >> 8) & 8191;
  int d0 = ((int)i & 255) << 2;
  int t = r & (SEQ - 1);
  const float* cw = dir ? cw_b : cw_f;
  const float* cb = dir ? cb_b : cb_f;
  const ushort* p = u_bf + dir * USLAB + (long)r * D_INNER + d0;
  ushort4 u0 = *(const ushort4*)p;
  ushort4 u1 = (t >= 1) ? *(const ushort4*)(p - 1024) : ushort4{0, 0, 0, 0};
  ushort4 u2 = (t >= 2) ? *(const ushort4*)(p - 2048) : ushort4{0, 0, 0, 0};
  ushort4 u3 = (t >= 3) ? *(const ushort4*)(p - 3072) : ushort4{0, 0, 0, 0};
  float4 bb = *(const float4*)(cb + d0);
  float ub0[4] = {b2f(u0.x), b2f(u0.y), b2f(u0.z), b2f(u0.w)};
  float ub1[4] = {b2f(u1.x), b2f(u1.y), b2f(u1.z), b2f(u1.w)};
  float ub2[4] = {b2f(u2.x), b2f(u2.y), b2f(u2.z), b2f(u2.w)};
  float ub3[4] = {b2f(u3.x), b2f(u3.y), b2f(u3.z), b2f(u3.w)};
  float bbv[4] = {bb.x, bb.y, bb.z, bb.w};
  ushort ov[4];
#pragma unroll
  for (int j = 0; j < 4; ++j) {
    float4 wj = *(const float4*)(cw + (d0 + j) * 4);
    float acc = bbv[j];
    acc = fmaf(wj.w, ub0[j], acc);
    acc = fmaf(wj.z, ub1[j], acc);
    acc = fmaf(wj.y, ub2[j], acc);
    acc = fmaf(wj.x, ub3[j], acc);
    ov[j] = f2b(acc * sigmoidf_(acc));
  }
  ushort4 o;
  o.x = ov[0]; o.y = ov[1]; o.z = ov[2]; o.w = ov[3];
  *(ushort4*)(uc_bf + dir * USLAB + (long)r * D_INNER + d0) = o;
}

// Decay powers E^(s+1), s=0..15, from E = exp(-dt).
#define EP_FAST(dt, Ep)                                        \
  {                                                            \
    float E1 = __expf(-(dt));                                  \
    float E2 = E1 * E1, E4 = E2 * E2, E8 = E4 * E4;            \
    Ep[0] = E1;  Ep[1] = E2;      Ep[2] = E2 * E1;             \
    Ep[3] = E4;  Ep[4] = E4 * E1; Ep[5] = E4 * E2;             \
    Ep[6] = E4 * Ep[2]; Ep[7] = E8;  Ep[8] = E8 * E1;          \
    Ep[9] = E8 * E2; Ep[10] = E8 * Ep[2]; Ep[11] = E8 * E4;    \
    Ep[12] = E8 * Ep[4]; Ep[13] = E8 * Ep[5];                  \
    Ep[14] = E8 * Ep[6]; Ep[15] = E8 * E8;                     \
  }

__device__ __forceinline__ bool a_is_arange(const float* Ar) {
  bool ok = true;
#pragma unroll
  for (int s = 0; s < D_STATE; ++s)
    ok = ok && (fabsf(Ar[s] + (float)(s + 1)) <= 1e-3f * (float)(s + 1));
  return ok;
}

// ---------------- chunked selective scan (both dirs in one grid) -----------
// idx bits: d[0:10) c[10:16) b[16:19) dir[19]
__global__ __launch_bounds__(256) void scan_partA(
    const ushort* __restrict__ delta_bf,  // [2][8192][1024]
    const ushort* __restrict__ ucv_bf,    // [2][8192][1024]
    const ushort* __restrict__ dblb,      // [2][8192][64]
    const float* __restrict__ A_log_f, const float* __restrict__ A_log_b,
    ushort* __restrict__ hend,            // [2][8][CH][16][1024] bf16
    float* __restrict__ dtsum_buf)        // [2][8][CH][1024]
{
  __shared__ float bc[CL][16];            // B rows of this chunk
  long idx = (long)blockIdx.x * 256 + threadIdx.x;
  int d = (int)idx & 1023;
  int c = ((int)idx >> 10) & (CH - 1);
  int b = ((int)idx >> 16) & 7;
  int dir = (int)(idx >> 19);
  const long r0 = (long)b * SEQ + c * CL;
  const ushort* dblp = dblb + (long)dir * NROWS * 64;
  {
    int tt = threadIdx.x >> 4, ss = threadIdx.x & 15;
    bc[tt][ss] = b2f(dblp[(r0 + tt) * 64 + 32 + ss]);
  }
  const float* Alog = dir ? A_log_b : A_log_f;
  const ushort* dp = delta_bf + dir * USLAB;
  const ushort* up = ucv_bf + dir * USLAB;
  float Ar[D_STATE];
#pragma unroll
  for (int s = 0; s < D_STATE; ++s) Ar[s] = -__expf(Alog[d * D_STATE + s]);
  const bool fast = a_is_arange(Ar);
  float h[D_STATE] = {0.f};
  float dtsum = 0.f;
  __syncthreads();

  if (fast) {
    for (int t = 0; t < CL; ++t) {
      long r = r0 + t;
      float dt = b2f(dp[r * 1024 + d]);
      float u  = b2f(up[r * 1024 + d]);
      float du = dt * u;
      dtsum += dt;
      float Ep[16];
      EP_FAST(dt, Ep);
#pragma unroll
      for (int s = 0; s < D_STATE; ++s)
        h[s] = fmaf(h[s], Ep[s], du * bc[t][s]);
    }
  } else {
    for (int t = 0; t < CL; ++t) {
      long r = r0 + t;
      float dt = b2f(dp[r * 1024 + d]);
      float u  = b2f(up[r * 1024 + d]);
      float du = dt * u;
      dtsum += dt;
#pragma unroll
      for (int s = 0; s < D_STATE; ++s)
        h[s] = fmaf(h[s], __expf(dt * Ar[s]), du * bc[t][s]);
    }
  }
  long base = ((long)((dir * 8 + b) * CH + c) * D_STATE) * 1024 + d;
#pragma unroll
  for (int s = 0; s < D_STATE; ++s) hend[base + s * 1024] = f2b(h[s]);
  dtsum_buf[(long)((dir * 8 + b) * CH + c) * 1024 + d] = dtsum;
}

// idx bits: d[0:10) s[10:14) b[14:17) dir[17]
__global__ __launch_bounds__(256) void scan_partB(
    ushort* __restrict__ hend,
    const float* __restrict__ dtsum_buf,
    const float* __restrict__ A_log_f, const float* __restrict__ A_log_b)
{
  long idx = (long)blockIdx.x * 256 + threadIdx.x;
  int d = (int)idx & 1023;
  int s = ((int)idx >> 10) & 15;
  int b = ((int)idx >> 14) & 7;
  int dir = (int)(idx >> 17);
  const float* Alog = dir ? A_log_b : A_log_f;
  float Ars = -__expf(Alog[d * D_STATE + s]);
  float H = 0.f;
  for (int c = 0; c < CH; ++c) {
    long off = ((long)((dir * 8 + b) * CH + c) * D_STATE + s) * 1024 + d;
    float he = b2f(hend[off]);
    float P = __expf(Ars * dtsum_buf[(long)((dir * 8 + b) * CH + c) * 1024 + d]);
    hend[off] = f2b(H);
    H = fmaf(P, H, he);
  }
}

__global__ __launch_bounds__(256) void scan_partC(
    const ushort* __restrict__ delta_bf,
    const ushort* __restrict__ ucv_bf,
    const ushort* __restrict__ dblb,
    const float* __restrict__ A_log_f, const float* __restrict__ A_log_b,
    const float* __restrict__ Dp_f, const float* __restrict__ Dp_b,
    const ushort* __restrict__ zsilu_bf,
    const ushort* __restrict__ hinit,
    ushort* __restrict__ ydz_bf)          // elementwise alias of ucv_bf
{
  __shared__ float bc[CL][32];
  long idx = (long)blockIdx.x * 256 + threadIdx.x;
  int d = (int)idx & 1023;
  int c = ((int)idx >> 10) & (CH - 1);
  int b = ((int)idx >> 16) & 7;
  int dir = (int)(idx >> 19);
  const long r0 = (long)b * SEQ + c * CL;
  const ushort* dblp = dblb + (long)dir * NROWS * 64;
  {
    int tt = threadIdx.x >> 4, cc = (threadIdx.x & 15) * 2;
    ushort2 v = *(const ushort2*)&dblp[(r0 + tt) * 64 + 32 + cc];
    bc[tt][cc] = b2f(v.x); bc[tt][cc + 1] = b2f(v.y);
  }
  const float* Alog = dir ? A_log_b : A_log_f;
  const ushort* dp = delta_bf + dir * USLAB;
  const ushort* up = ucv_bf + dir * USLAB;
  const ushort* zp = zsilu_bf + dir * USLAB;
  ushort* yp = ydz_bf + dir * USLAB;
  float Ar[D_STATE];
#pragma unroll
  for (int s = 0; s < D_STATE; ++s) Ar[s] = -__expf(Alog[d * D_STATE + s]);
  const bool fast = a_is_arange(Ar);
  float h[D_STATE];
  long base = ((long)((dir * 8 + b) * CH + c) * D_STATE) * 1024 + d;
#pragma unroll
  for (int s = 0; s < D_STATE; ++s) h[s] = b2f(hinit[base + s * 1024]);
  float Dd = (dir ? Dp_b : Dp_f)[d];
  __syncthreads();

  if (fast) {
    for (int t = 0; t < CL; ++t) {
      long r = r0 + t;
      float dt = b2f(dp[r * 1024 + d]);
      float u  = b2f(up[r * 1024 + d]);
      float du = dt * u;
      float Ep[16];
      EP_FAST(dt, Ep);
      float y = 0.f;
#pragma unroll
      for (int s = 0; s < D_STATE; ++s) {
        h[s] = fmaf(h[s], Ep[s], du * bc[t][s]);
        y = fmaf(h[s], bc[t][16 + s], y);
      }
      float zs = b2f(zp[r * 1024 + d]);
      float yv = fmaf(u, Dd, y);
      yp[r * 1024 + d] = f2b(yv * zs);
    }
  } else {
    for (int t = 0; t < CL; ++t) {
      long r = r0 + t;
      float dt = b2f(dp[r * 1024 + d]);
      float u  = b2f(up[r * 1024 + d]);
      float du = dt * u;
      float y = 0.f;
#pragma unroll
      for (int s = 0; s < D_STATE; ++s) {
        h[s] = fmaf(h[s], __expf(dt * Ar[s]), du * bc[t][s]);
        y = fmaf(h[s], bc[t][16 + s], y);
      }
      float zs = b2f(zp[r * 1024 + d]);
      float yv = fmaf(u, Dd, y);
      yp[r * 1024 + d] = f2b(yv * zs);
    }
  }
}

extern "C" void kernel_launch(void* const* d_in, const int* in_sizes, int n_in,
                              void* d_out, int out_size, void* d_ws, size_t ws_size,
                              hipStream_t stream)
{
  const float* x = (const float*)d_in[0];
  float* out = (float*)d_out;
  char* ws = (char*)d_ws;
  // Layout (MiB offsets), total 136 MiB:
  ushort* zsilu  = (ushort*)(ws);                     // 32: [2][8192][1024]
  ushort* ucv    = (ushort*)(ws + (32ul << 20));      // 32: [2][8192][1024] (=ydz)
  ushort* u_bf   = (ushort*)(ws + (64ul << 20));      // 32: [2][8192][1024] (=delta)
  ushort* hend   = (ushort*)(ws + (96ul << 20));      // 32: [2][8][CH][16][1024] bf16
  float*  dtsum  = (float*)(ws + (128ul << 20));      //  4: [2][8][CH][1024]
  ushort* dblb   = (ushort*)(ws + (132ul << 20));     //  2: [2][8192][64]
  ushort* out_wb = (ushort*)(ws + (134ul << 20));     //  2: [2][512][1024]
  // transient aliases inside hend slab (dead before scan_partA writes hend):
  ushort* xbf    = hend;                              //  8: [8192][512]
  ushort* in_wb  = hend + (8ul << 19);                //  4: [4096][512]  (8 MiB in)
  ushort* xp_wb  = hend + (12ul << 19);               // .25: [2][64][1024]
  ushort* dt_wb  = xp_wb + 131072;                    // .125: [2][1024][32]
  ushort* delta  = u_bf;
  ushort* ydz    = ucv;

  ConvArgs ca;
  int bcur = 0, si = 0;
  auto addseg = [&](const float* s, ushort* d, int nelem) {
    ca.seg[si].s = (const float4*)s; ca.seg[si].d = (ushort4*)d;
    ca.seg[si].n4 = nelem / 4; ca.seg[si].bstart = bcur;
    bcur += (nelem / 4 + 255) / 256; ++si;
  };
  addseg(x, xbf, NROWS * D_MODEL);
  addseg((const float*)d_in[1], in_wb, 2048 * 512);           // in_w_f
  addseg((const float*)d_in[10], in_wb + 2048 * 512, 2048 * 512); // in_w_b
  addseg((const float*)d_in[9], out_wb, 512 * 1024);          // out_w_f
  addseg((const float*)d_in[18], out_wb + 512 * 1024, 512 * 1024);
  addseg((const float*)d_in[4], xp_wb, 64 * 1024);            // xp_w_f
  addseg((const float*)d_in[13], xp_wb + 65536, 64 * 1024);
  addseg((const float*)d_in[5], dt_wb, 1024 * 32);            // dt_w_f
  addseg((const float*)d_in[14], dt_wb + 32768, 1024 * 32);

  dim3 blk(256);
  convert_all<<<dim3(bcur), blk, 0, stream>>>(ca);

  // 1) merged in_proj: [8192,4096] -> u/zsilu per dir (bwd rows reversed)
  gemm_bf16<128, 128, 2, 2, 2, 0, 0><<<dim3(32, 64), blk, 0, stream>>>(
      xbf, D_MODEL, nullptr, in_wb, D_MODEL, nullptr,
      nullptr, u_bf, zsilu, 0, D_MODEL, nullptr, nullptr, 0, 0, 0);
  // 2) conv + silu, both dirs
  conv_silu<<<dim3(2 * NROWS), blk, 0, stream>>>(
      u_bf, (const float*)d_in[2], (const float*)d_in[11],
      (const float*)d_in[3], (const float*)d_in[12], ucv);
  // 3) x_proj, both dirs in one block-diag dispatch: M=16384, BM=64
  gemm_bf16<64, 64, 2, 2, 4, 0, 1><<<dim3(1, 256), blk, 0, stream>>>(
      ucv, D_INNER, nullptr, xp_wb, D_INNER, nullptr,
      nullptr, dblb, nullptr, 64, D_INNER, nullptr, nullptr, 65536, 0, 0);
  // 4) dt_proj + softplus, both dirs block-diag: M=16384, K=32
  gemm_bf16<128, 128, 2, 2, 1, 0, 1><<<dim3(8, 128), blk, 0, stream>>>(
      dblb, 64, nullptr, dt_wb, DT_RANK, nullptr,
      nullptr, delta, nullptr, D_INNER, DT_RANK,
      (const float*)d_in[6], (const float*)d_in[15], 32768, 0, 0);
  // 5) chunked scan, both dirs
  const float* Alf = (const float*)d_in[7];
  const float* Alb = (const float*)d_in[16];
  scan_partA<<<dim3(2 * BATCH * CH * 1024 / 256), blk, 0, stream>>>(
      delta, ucv, dblb, Alf, Alb, hend, dtsum);
  scan_partB<<<dim3(2 * BATCH * 16 * 1024 / 256), blk, 0, stream>>>(
      hend, dtsum, Alf, Alb);
  scan_partC<<<dim3(2 * BATCH * CH * 1024 / 256), blk, 0, stream>>>(
      delta, ucv, dblb, Alf, Alb,
      (const float*)d_in[8], (const float*)d_in[17], zsilu, hend, ydz);
  // 6) out_proj, both dirs in one K=2048 dispatch (bwd half: reversed rows)
  gemm_bf16<128, 128, 2, 2, 0, 1, 0><<<dim3(4, 64), blk, 0, stream>>>(
      ydz, D_INNER, ydz + USLAB, out_wb, D_INNER, out_wb + 512 * 1024,
      out, nullptr, nullptr, D_MODEL, 2 * D_INNER, nullptr, nullptr, 0, 0, 0);
}

// Round 10
// 257.724 us; speedup vs baseline: 10.3489x; 1.1668x over previous
//
#include <hip/hip_runtime.h>
#include <math.h>

#define BATCH 8
#define SEQ 1024
#define D_MODEL 512
#define D_INNER 1024
#define D_STATE 16
#define DT_RANK 32
#define NROWS (BATCH * SEQ)   // 8192
#define CH 64                 // chunks per sequence
#define CL 16                 // chunk length
#define USLAB 8388608l        // 8192*1024 elems (one dir slab)

typedef short short8 __attribute__((ext_vector_type(8)));
typedef float f32x4 __attribute__((ext_vector_type(4)));

__device__ __forceinline__ float sigmoidf_(float x) { return 1.f / (1.f + __expf(-x)); }

// fast softplus: log1pf is libm-precise (~270 VALU ops measured, R9); the
// hw-approx v_exp+v_log composition is ~8 ops, rel err ~1e-6 << bf16 rounding.
__device__ __forceinline__ float softplus_(float v) {
  return (v > 20.f) ? v : __logf(1.f + __expf(v));
}

__device__ __forceinline__ ushort f2b(float f) {  // fp32 -> bf16 RNE
  uint u = __float_as_uint(f);
  return (ushort)((u + 0x7FFFu + ((u >> 16) & 1u)) >> 16);
}
__device__ __forceinline__ float b2f(ushort u) {
  return __uint_as_float(((uint)u) << 16);
}

__device__ __forceinline__ void gload16(const ushort* g, const ushort* l) {
  __builtin_amdgcn_global_load_lds(
      (const __attribute__((address_space(1))) void*)g,
      (__attribute__((address_space(3))) void*)l, 16, 0, 0);
}

__device__ __forceinline__ int revrow(int m) {
  return (m & ~1023) | (1023 - (m & 1023));
}

// ---------------- bf16 MFMA GEMM: 2-phase dbuf + T2 swizzle + T1 -----------
// C[m,n] = sum_k A[m,k]*B[n,k]; BMxBN tile, 4 waves, BK=32.
// EPI: 0 = fp32 store (revC/accumC)
//      1 = softplus(v+bias[n]) -> Cb bf16
//      2 = merged in_proj: n -> {dir, u|z}; bwd rows reversed; z gets silu
//      4 = plain bf16 -> Cb
// DUALK: K spans two slabs; for k0 >= K/2 use A2 (rows reversed) and B2.
// MDIAG: block-diagonal over M: rows >= 8192 use B + b_stride, bias2.
template<int BM, int BN, int RW, int CW, int EPI, int DUALK, int MDIAG>
__global__ __launch_bounds__(256) void gemm_bf16(
    const ushort* __restrict__ A, int lda, const ushort* __restrict__ A2,
    const ushort* __restrict__ B, int ldb, const ushort* __restrict__ B2,
    float* __restrict__ Cf, ushort* __restrict__ Cb, ushort* __restrict__ Cb2,
    int ldc, int K, const float* __restrict__ bias, const float* __restrict__ bias2,
    int b_stride, int revC, int accumC)
{
  constexpr int MI = BM / RW / 16;
  constexpr int NJ = BN / CW / 16;
  __shared__ ushort As[2][BM * 32];
  __shared__ ushort Bs[2][BN * 32];
  const int tid = threadIdx.x;
  const int w = tid >> 6, lane = tid & 63;

  const int nwg = gridDim.x * gridDim.y;
  int bid = blockIdx.y * gridDim.x + blockIdx.x;
  int wgid = (bid & 7) * (nwg >> 3) + (bid >> 3);
  const int bm = (wgid / gridDim.x) * BM;
  const int bn = (wgid % gridDim.x) * BN;

  if (MDIAG) {
    int mdir = (bm >= NROWS) ? 1 : 0;
    B += mdir * b_stride;
    if (mdir) bias = bias2;
  }

  const int rw0 = (w / CW) * (MI * 16);
  const int cw0 = (w % CW) * (NJ * 16);
  const int srow = w * 16 + (lane >> 2);
  const int scol = (((lane & 3) ^ ((lane >> 3) & 3)) << 3);
  const int rchunk = (((lane >> 4) ^ (((lane & 15) >> 1) & 3)) << 3);

  f32x4 acc[MI][NJ] = {};

  auto stage = [&](int buf, int k0) {
    const ushort* Ap = A;
    const ushort* Bp = B;
    int kc = k0;
    bool hi = false;
    if (DUALK && k0 >= (K >> 1)) { Ap = A2; Bp = B2; kc = k0 - (K >> 1); hi = true; }
#pragma unroll
    for (int it = 0; it < BM / 64; ++it) {
      int gm = bm + it * 64 + srow;
      int arow = (DUALK && hi) ? revrow(gm) : gm;
      gload16(Ap + (long)arow * lda + kc + scol, &As[buf][(it * 64 + w * 16) * 32]);
    }
#pragma unroll
    for (int it = 0; it < BN / 64; ++it) {
      int gn = bn + it * 64 + srow;
      gload16(Bp + (long)gn * ldb + kc + scol, &Bs[buf][(it * 64 + w * 16) * 32]);
    }
  };

  stage(0, 0);
  __syncthreads();

  for (int k0 = 0; k0 < K; k0 += 32) {
    int cur = (k0 >> 5) & 1;
    if (k0 + 32 < K) stage(cur ^ 1, k0 + 32);
    short8 a[MI], b[NJ];
#pragma unroll
    for (int i = 0; i < MI; ++i)
      a[i] = *(const short8*)&As[cur][(rw0 + i * 16 + (lane & 15)) * 32 + rchunk];
#pragma unroll
    for (int j = 0; j < NJ; ++j)
      b[j] = *(const short8*)&Bs[cur][(cw0 + j * 16 + (lane & 15)) * 32 + rchunk];
#pragma unroll
    for (int i = 0; i < MI; ++i)
#pragma unroll
      for (int j = 0; j < NJ; ++j)
        acc[i][j] = __builtin_amdgcn_mfma_f32_16x16x32_bf16(a[i], b[j], acc[i][j], 0, 0, 0);
    __syncthreads();
  }

#pragma unroll
  for (int i = 0; i < MI; ++i)
#pragma unroll
    for (int r = 0; r < 4; ++r) {
      int m = bm + rw0 + i * 16 + (lane >> 4) * 4 + r;
      int crow = revC ? revrow(m) : m;
#pragma unroll
      for (int j = 0; j < NJ; ++j) {
        int n = bn + cw0 + j * 16 + (lane & 15);
        float v = acc[i][j][r];
        if (EPI == 0) {
          float* p = Cf + (long)crow * ldc + n;
          if (accumC) *p += v; else *p = v;
        } else if (EPI == 1) {
          Cb[(long)crow * ldc + n] = f2b(softplus_(v + bias[n]));
        } else if (EPI == 2) {
          int dir = n >> 11;          // 0 = fwd, 1 = bwd
          int nn = n & 2047;          // within-dir col
          int sub = nn & 1023;
          int row = dir ? revrow(m) : m;
          if (nn < D_INNER)
            Cb[dir * USLAB + (long)row * 1024 + sub] = f2b(v);
          else
            Cb2[dir * USLAB + (long)row * 1024 + sub] = f2b(v * sigmoidf_(v));
        } else {  // EPI == 4
          Cb[(long)crow * ldc + n] = f2b(v);
        }
      }
    }
}

// ---------------- fused fp32->bf16 converter (x + 8 weight tensors) --------
struct Seg { const float4* s; ushort4* d; int n4; int bstart; };
struct ConvArgs { Seg seg[9]; };

__global__ __launch_bounds__(256) void convert_all(ConvArgs a)
{
  int blk = blockIdx.x;
  int i = 0;
#pragma unroll
  for (int k = 1; k < 9; ++k) if (blk >= a.seg[k].bstart) i = k;
  int idx = (blk - a.seg[i].bstart) * 256 + threadIdx.x;
  if (idx >= a.seg[i].n4) return;
  float4 v = a.seg[i].s[idx];
  ushort4 o;
  o.x = f2b(v.x); o.y = f2b(v.y); o.z = f2b(v.z); o.w = f2b(v.w);
  a.seg[i].d[idx] = o;
}

// ------------- conv1d(k=4) + bias + silu, both dirs (4 d/thread) -----------
__global__ __launch_bounds__(256) void conv_silu(
    const ushort* __restrict__ u_bf,   // [2][8192][1024]
    const float* __restrict__ cw_f, const float* __restrict__ cw_b,
    const float* __restrict__ cb_f, const float* __restrict__ cb_b,
    ushort* __restrict__ uc_bf)        // [2][8192][1024]
{
  long i = (long)blockIdx.x * 256 + threadIdx.x;
  int dir = (int)(i >> 21);
  int r = (int)(i >> 8) & 8191;
  int d0 = ((int)i & 255) << 2;
  int t = r & (SEQ - 1);
  const float* cw = dir ? cw_b : cw_f;
  const float* cb = dir ? cb_b : cb_f;
  const ushort* p = u_bf + dir * USLAB + (long)r * D_INNER + d0;
  ushort4 u0 = *(const ushort4*)p;
  ushort4 u1 = (t >= 1) ? *(const ushort4*)(p - 1024) : ushort4{0, 0, 0, 0};
  ushort4 u2 = (t >= 2) ? *(const ushort4*)(p - 2048) : ushort4{0, 0, 0, 0};
  ushort4 u3 = (t >= 3) ? *(const ushort4*)(p - 3072) : ushort4{0, 0, 0, 0};
  float4 bb = *(const float4*)(cb + d0);
  float ub0[4] = {b2f(u0.x), b2f(u0.y), b2f(u0.z), b2f(u0.w)};
  float ub1[4] = {b2f(u1.x), b2f(u1.y), b2f(u1.z), b2f(u1.w)};
  float ub2[4] = {b2f(u2.x), b2f(u2.y), b2f(u2.z), b2f(u2.w)};
  float ub3[4] = {b2f(u3.x), b2f(u3.y), b2f(u3.z), b2f(u3.w)};
  float bbv[4] = {bb.x, bb.y, bb.z, bb.w};
  ushort ov[4];
#pragma unroll
  for (int j = 0; j < 4; ++j) {
    float4 wj = *(const float4*)(cw + (d0 + j) * 4);
    float acc = bbv[j];
    acc = fmaf(wj.w, ub0[j], acc);
    acc = fmaf(wj.z, ub1[j], acc);
    acc = fmaf(wj.y, ub2[j], acc);
    acc = fmaf(wj.x, ub3[j], acc);
    ov[j] = f2b(acc * sigmoidf_(acc));
  }
  ushort4 o;
  o.x = ov[0]; o.y = ov[1]; o.z = ov[2]; o.w = ov[3];
  *(ushort4*)(uc_bf + dir * USLAB + (long)r * D_INNER + d0) = o;
}

// Decay powers E^(s+1), s=0..15, from E = exp(-dt).
#define EP_FAST(dt, Ep)                                        \
  {                                                            \
    float E1 = __expf(-(dt));                                  \
    float E2 = E1 * E1, E4 = E2 * E2, E8 = E4 * E4;            \
    Ep[0] = E1;  Ep[1] = E2;      Ep[2] = E2 * E1;             \
    Ep[3] = E4;  Ep[4] = E4 * E1; Ep[5] = E4 * E2;             \
    Ep[6] = E4 * Ep[2]; Ep[7] = E8;  Ep[8] = E8 * E1;          \
    Ep[9] = E8 * E2; Ep[10] = E8 * Ep[2]; Ep[11] = E8 * E4;    \
    Ep[12] = E8 * Ep[4]; Ep[13] = E8 * Ep[5];                  \
    Ep[14] = E8 * Ep[6]; Ep[15] = E8 * E8;                     \
  }

__device__ __forceinline__ bool a_is_arange(const float* Ar) {
  bool ok = true;
#pragma unroll
  for (int s = 0; s < D_STATE; ++s)
    ok = ok && (fabsf(Ar[s] + (float)(s + 1)) <= 1e-3f * (float)(s + 1));
  return ok;
}

// ---------------- chunked selective scan (both dirs in one grid) -----------
// idx bits: d[0:10) c[10:16) b[16:19) dir[19]
__global__ __launch_bounds__(256) void scan_partA(
    const ushort* __restrict__ delta_bf,  // [2][8192][1024]
    const ushort* __restrict__ ucv_bf,    // [2][8192][1024]
    const ushort* __restrict__ dblb,      // [2][8192][64]
    const float* __restrict__ A_log_f, const float* __restrict__ A_log_b,
    ushort* __restrict__ hend,            // [2][8][CH][16][1024] bf16
    float* __restrict__ dtsum_buf)        // [2][8][CH][1024]
{
  __shared__ float bc[CL][16];            // B rows of this chunk
  long idx = (long)blockIdx.x * 256 + threadIdx.x;
  int d = (int)idx & 1023;
  int c = ((int)idx >> 10) & (CH - 1);
  int b = ((int)idx >> 16) & 7;
  int dir = (int)(idx >> 19);
  const long r0 = (long)b * SEQ + c * CL;
  const ushort* dblp = dblb + (long)dir * NROWS * 64;
  {
    int tt = threadIdx.x >> 4, ss = threadIdx.x & 15;
    bc[tt][ss] = b2f(dblp[(r0 + tt) * 64 + 32 + ss]);
  }
  const float* Alog = dir ? A_log_b : A_log_f;
  const ushort* dp = delta_bf + dir * USLAB;
  const ushort* up = ucv_bf + dir * USLAB;
  float Ar[D_STATE];
#pragma unroll
  for (int s = 0; s < D_STATE; ++s) Ar[s] = -__expf(Alog[d * D_STATE + s]);
  const bool fast = a_is_arange(Ar);
  float h[D_STATE] = {0.f};
  float dtsum = 0.f;
  __syncthreads();

  if (fast) {
    for (int t = 0; t < CL; ++t) {
      long r = r0 + t;
      float dt = b2f(dp[r * 1024 + d]);
      float u  = b2f(up[r * 1024 + d]);
      float du = dt * u;
      dtsum += dt;
      float Ep[16];
      EP_FAST(dt, Ep);
#pragma unroll
      for (int s = 0; s < D_STATE; ++s)
        h[s] = fmaf(h[s], Ep[s], du * bc[t][s]);
    }
  } else {
    for (int t = 0; t < CL; ++t) {
      long r = r0 + t;
      float dt = b2f(dp[r * 1024 + d]);
      float u  = b2f(up[r * 1024 + d]);
      float du = dt * u;
      dtsum += dt;
#pragma unroll
      for (int s = 0; s < D_STATE; ++s)
        h[s] = fmaf(h[s], __expf(dt * Ar[s]), du * bc[t][s]);
    }
  }
  long base = ((long)((dir * 8 + b) * CH + c) * D_STATE) * 1024 + d;
#pragma unroll
  for (int s = 0; s < D_STATE; ++s) hend[base + s * 1024] = f2b(h[s]);
  dtsum_buf[(long)((dir * 8 + b) * CH + c) * 1024 + d] = dtsum;
}

// idx bits: d[0:10) s[10:14) b[14:17) dir[17]
__global__ __launch_bounds__(256) void scan_partB(
    ushort* __restrict__ hend,
    const float* __restrict__ dtsum_buf,
    const float* __restrict__ A_log_f, const float* __restrict__ A_log_b)
{
  long idx = (long)blockIdx.x * 256 + threadIdx.x;
  int d = (int)idx & 1023;
  int s = ((int)idx >> 10) & 15;
  int b = ((int)idx >> 14) & 7;
  int dir = (int)(idx >> 17);
  const float* Alog = dir ? A_log_b : A_log_f;
  float Ars = -__expf(Alog[d * D_STATE + s]);
  float H = 0.f;
  for (int c = 0; c < CH; ++c) {
    long off = ((long)((dir * 8 + b) * CH + c) * D_STATE + s) * 1024 + d;
    float he = b2f(hend[off]);
    float P = __expf(Ars * dtsum_buf[(long)((dir * 8 + b) * CH + c) * 1024 + d]);
    hend[off] = f2b(H);
    H = fmaf(P, H, he);
  }
}

__global__ __launch_bounds__(256) void scan_partC(
    const ushort* __restrict__ delta_bf,
    const ushort* __restrict__ ucv_bf,
    const ushort* __restrict__ dblb,
    const float* __restrict__ A_log_f, const float* __restrict__ A_log_b,
    const float* __restrict__ Dp_f, const float* __restrict__ Dp_b,
    const ushort* __restrict__ zsilu_bf,
    const ushort* __restrict__ hinit,
    ushort* __restrict__ ydz_bf)          // elementwise alias of ucv_bf
{
  __shared__ float bc[CL][32];
  long idx = (long)blockIdx.x * 256 + threadIdx.x;
  int d = (int)idx & 1023;
  int c = ((int)idx >> 10) & (CH - 1);
  int b = ((int)idx >> 16) & 7;
  int dir = (int)(idx >> 19);
  const long r0 = (long)b * SEQ + c * CL;
  const ushort* dblp = dblb + (long)dir * NROWS * 64;
  {
    int tt = threadIdx.x >> 4, cc = (threadIdx.x & 15) * 2;
    ushort2 v = *(const ushort2*)&dblp[(r0 + tt) * 64 + 32 + cc];
    bc[tt][cc] = b2f(v.x); bc[tt][cc + 1] = b2f(v.y);
  }
  const float* Alog = dir ? A_log_b : A_log_f;
  const ushort* dp = delta_bf + dir * USLAB;
  const ushort* up = ucv_bf + dir * USLAB;
  const ushort* zp = zsilu_bf + dir * USLAB;
  ushort* yp = ydz_bf + dir * USLAB;
  float Ar[D_STATE];
#pragma unroll
  for (int s = 0; s < D_STATE; ++s) Ar[s] = -__expf(Alog[d * D_STATE + s]);
  const bool fast = a_is_arange(Ar);
  float h[D_STATE];
  long base = ((long)((dir * 8 + b) * CH + c) * D_STATE) * 1024 + d;
#pragma unroll
  for (int s = 0; s < D_STATE; ++s) h[s] = b2f(hinit[base + s * 1024]);
  float Dd = (dir ? Dp_b : Dp_f)[d];
  __syncthreads();

  if (fast) {
    for (int t = 0; t < CL; ++t) {
      long r = r0 + t;
      float dt = b2f(dp[r * 1024 + d]);
      float u  = b2f(up[r * 1024 + d]);
      float du = dt * u;
      float Ep[16];
      EP_FAST(dt, Ep);
      float y = 0.f;
#pragma unroll
      for (int s = 0; s < D_STATE; ++s) {
        h[s] = fmaf(h[s], Ep[s], du * bc[t][s]);
        y = fmaf(h[s], bc[t][16 + s], y);
      }
      float zs = b2f(zp[r * 1024 + d]);
      float yv = fmaf(u, Dd, y);
      yp[r * 1024 + d] = f2b(yv * zs);
    }
  } else {
    for (int t = 0; t < CL; ++t) {
      long r = r0 + t;
      float dt = b2f(dp[r * 1024 + d]);
      float u  = b2f(up[r * 1024 + d]);
      float du = dt * u;
      float y = 0.f;
#pragma unroll
      for (int s = 0; s < D_STATE; ++s) {
        h[s] = fmaf(h[s], __expf(dt * Ar[s]), du * bc[t][s]);
        y = fmaf(h[s], bc[t][16 + s], y);
      }
      float zs = b2f(zp[r * 1024 + d]);
      float yv = fmaf(u, Dd, y);
      yp[r * 1024 + d] = f2b(yv * zs);
    }
  }
}

extern "C" void kernel_launch(void* const* d_in, const int* in_sizes, int n_in,
                              void* d_out, int out_size, void* d_ws, size_t ws_size,
                              hipStream_t stream)
{
  const float* x = (const float*)d_in[0];
  float* out = (float*)d_out;
  char* ws = (char*)d_ws;
  // Layout (MiB offsets), total 136 MiB:
  ushort* zsilu  = (ushort*)(ws);                     // 32: [2][8192][1024]
  ushort* ucv    = (ushort*)(ws + (32ul << 20));      // 32: [2][8192][1024] (=ydz)
  ushort* u_bf   = (ushort*)(ws + (64ul << 20));      // 32: [2][8192][1024] (=delta)
  ushort* hend   = (ushort*)(ws + (96ul << 20));      // 32: [2][8][CH][16][1024] bf16
  float*  dtsum  = (float*)(ws + (128ul << 20));      //  4: [2][8][CH][1024]
  ushort* dblb   = (ushort*)(ws + (132ul << 20));     //  2: [2][8192][64]
  ushort* out_wb = (ushort*)(ws + (134ul << 20));     //  2: [2][512][1024]
  // transient aliases inside hend slab (dead before scan_partA writes hend):
  ushort* xbf    = hend;                              //  8: [8192][512]
  ushort* in_wb  = hend + (8ul << 19);                //  4: [4096][512]  (8 MiB in)
  ushort* xp_wb  = hend + (12ul << 19);               // .25: [2][64][1024]
  ushort* dt_wb  = xp_wb + 131072;                    // .125: [2][1024][32]
  ushort* delta  = u_bf;
  ushort* ydz    = ucv;

  ConvArgs ca;
  int bcur = 0, si = 0;
  auto addseg = [&](const float* s, ushort* d, int nelem) {
    ca.seg[si].s = (const float4*)s; ca.seg[si].d = (ushort4*)d;
    ca.seg[si].n4 = nelem / 4; ca.seg[si].bstart = bcur;
    bcur += (nelem / 4 + 255) / 256; ++si;
  };
  addseg(x, xbf, NROWS * D_MODEL);
  addseg((const float*)d_in[1], in_wb, 2048 * 512);           // in_w_f
  addseg((const float*)d_in[10], in_wb + 2048 * 512, 2048 * 512); // in_w_b
  addseg((const float*)d_in[9], out_wb, 512 * 1024);          // out_w_f
  addseg((const float*)d_in[18], out_wb + 512 * 1024, 512 * 1024);
  addseg((const float*)d_in[4], xp_wb, 64 * 1024);            // xp_w_f
  addseg((const float*)d_in[13], xp_wb + 65536, 64 * 1024);
  addseg((const float*)d_in[5], dt_wb, 1024 * 32);            // dt_w_f
  addseg((const float*)d_in[14], dt_wb + 32768, 1024 * 32);

  dim3 blk(256);
  convert_all<<<dim3(bcur), blk, 0, stream>>>(ca);

  // 1) merged in_proj: [8192,4096] -> u/zsilu per dir (bwd rows reversed)
  gemm_bf16<128, 128, 2, 2, 2, 0, 0><<<dim3(32, 64), blk, 0, stream>>>(
      xbf, D_MODEL, nullptr, in_wb, D_MODEL, nullptr,
      nullptr, u_bf, zsilu, 0, D_MODEL, nullptr, nullptr, 0, 0, 0);
  // 2) conv + silu, both dirs
  conv_silu<<<dim3(2 * NROWS), blk, 0, stream>>>(
      u_bf, (const float*)d_in[2], (const float*)d_in[11],
      (const float*)d_in[3], (const float*)d_in[12], ucv);
  // 3) x_proj, both dirs in one block-diag dispatch: M=16384, BM=64
  gemm_bf16<64, 64, 2, 2, 4, 0, 1><<<dim3(1, 256), blk, 0, stream>>>(
      ucv, D_INNER, nullptr, xp_wb, D_INNER, nullptr,
      nullptr, dblb, nullptr, 64, D_INNER, nullptr, nullptr, 65536, 0, 0);
  // 4) dt_proj + softplus, both dirs block-diag: M=16384, K=32
  gemm_bf16<128, 128, 2, 2, 1, 0, 1><<<dim3(8, 128), blk, 0, stream>>>(
      dblb, 64, nullptr, dt_wb, DT_RANK, nullptr,
      nullptr, delta, nullptr, D_INNER, DT_RANK,
      (const float*)d_in[6], (const float*)d_in[15], 32768, 0, 0);
  // 5) chunked scan, both dirs
  const float* Alf = (const float*)d_in[7];
  const float* Alb = (const float*)d_in[16];
  scan_partA<<<dim3(2 * BATCH * CH * 1024 / 256), blk, 0, stream>>>(
      delta, ucv, dblb, Alf, Alb, hend, dtsum);
  scan_partB<<<dim3(2 * BATCH * 16 * 1024 / 256), blk, 0, stream>>>(
      hend, dtsum, Alf, Alb);
  scan_partC<<<dim3(2 * BATCH * CH * 1024 / 256), blk, 0, stream>>>(
      delta, ucv, dblb, Alf, Alb,
      (const float*)d_in[8], (const float*)d_in[17], zsilu, hend, ydz);
  // 6) out_proj, both dirs in one K=2048 dispatch (bwd half: reversed rows)
  gemm_bf16<128, 128, 2, 2, 0, 1, 0><<<dim3(4, 64), blk, 0, stream>>>(
      ydz, D_INNER, ydz + USLAB, out_wb, D_INNER, out_wb + 512 * 1024,
      out, nullptr, nullptr, D_MODEL, 2 * D_INNER, nullptr, nullptr, 0, 0, 0);
}